// Round 9
// baseline (539.625 us; speedup 1.0000x reference)
//
#include <hip/hip_runtime.h>
#include <math.h>

#define N_PIX 4096  // H*W = 64*64
#define BATCH 4
#define LOG2E 1.4426950408889634f

typedef __bf16 bf16x8 __attribute__((ext_vector_type(8)));
typedef __bf16 bf16x4v __attribute__((ext_vector_type(4)));
typedef float f32x4 __attribute__((ext_vector_type(4)));

// fp8 e4m3 (OCP on gfx950) pack/unpack via HW cvt builtins
__device__ __forceinline__ unsigned pack4_fp8(float a, float b, float c, float d) {
    unsigned p = __builtin_amdgcn_cvt_pk_fp8_f32(a, b, 0, false);
    p = __builtin_amdgcn_cvt_pk_fp8_f32(c, d, p, true);
    return p;
}
__device__ __forceinline__ uint8_t to_fp8(float v) {
    return (uint8_t)(__builtin_amdgcn_cvt_pk_fp8_f32(v, v, 0, false) & 0xff);
}

// ---------------------------------------------------------------------------
// Spectral norm, parallel 3-phase version.
// sigma = ||W (W^T u)|| / ||W^T u||  (intermediate normalization cancels).
// ---------------------------------------------------------------------------
struct SigP {
    const float* W[5];
    const float* u[5];
    int O[5];
    int C[5];
};

// block -> (layer, 64-row chunk): counts {1,2,4,8,1}
__device__ __forceinline__ void sig_map(int bid, int& L, int& ch) {
    if (bid == 0)      { L = 0; ch = 0; }
    else if (bid < 3)  { L = 1; ch = bid - 1; }
    else if (bid < 7)  { L = 2; ch = bid - 3; }
    else if (bid < 15) { L = 3; ch = bid - 7; }
    else               { L = 4; ch = 0; }
}

__global__ __launch_bounds__(256)
void sigma_p1(SigP p, float* __restrict__ ybuf) {
    __shared__ float ush[64];
    int L, ch;
    sig_map(blockIdx.x, L, ch);
    const float* W = p.W[L];
    const float* u = p.u[L];
    int O = p.O[L], C = p.C[L];
    int o0 = ch * 64;
    int no = O - o0; if (no > 64) no = 64;
    int t = threadIdx.x;
    if (t < 64) ush[t] = (t < no) ? u[o0 + t] : 0.f;
    __syncthreads();
    for (int c = t; c < C; c += 256) {
        float a = 0.f;
        for (int o = 0; o < no; ++o) a += W[(size_t)(o0 + o) * C + c] * ush[o];
        atomicAdd(&ybuf[L * 512 + c], a);
    }
}

__global__ __launch_bounds__(256)
void sigma_p2(SigP p, const float* __restrict__ ybuf,
              float* __restrict__ S1, float* __restrict__ S2) {
    __shared__ float ysh[512];
    int L, ch;
    sig_map(blockIdx.x, L, ch);
    const float* W = p.W[L];
    int O = p.O[L], C = p.C[L];
    int o0 = ch * 64;
    int o_hi = o0 + 64; if (o_hi > O) o_hi = O;
    int t = threadIdx.x;
    int lane = t & 63, w = t >> 6;
    for (int c = t; c < C; c += 256) ysh[c] = ybuf[L * 512 + c];
    __syncthreads();

    if (ch == 0) {
        float s = 0.f;
        for (int c = t; c < C; c += 256) s += ysh[c] * ysh[c];
        #pragma unroll
        for (int off = 1; off < 64; off <<= 1) s += __shfl_xor(s, off);
        if (lane == 0) atomicAdd(&S1[L], s);
    }

    float sq = 0.f;
    for (int i = 0; i < 16; ++i) {
        int o = o0 + w * 16 + i;
        if (o >= o_hi) break;
        float a = 0.f;
        for (int c = lane; c < C; c += 64) a += W[(size_t)o * C + c] * ysh[c];
        #pragma unroll
        for (int off = 1; off < 64; off <<= 1) a += __shfl_xor(a, off);
        if (lane == 0) sq += a * a;
    }
    if (lane == 0) atomicAdd(&S2[L], sq);
}

// ---------------------------------------------------------------------------
// Weight split: (O,C) fp32 * iv * scale -> (O, 2C) bf16  [hi | lo].
// ---------------------------------------------------------------------------
__global__ __launch_bounds__(256)
void wsplit_kernel(const float* __restrict__ W, const float* __restrict__ iv,
                   float scale, int C, __bf16* __restrict__ out) {
    int o = blockIdx.x;
    float s = (iv ? iv[0] : 1.f) * scale;
    for (int c = threadIdx.x; c < C; c += 256) {
        float wv = W[(size_t)o * C + c] * s;
        __bf16 hi = (__bf16)wv;
        float lo = wv - (float)hi;
        out[(size_t)o * 2 * C + c] = hi;
        out[(size_t)o * 2 * C + C + c] = (__bf16)lo;
    }
}

// ---------------------------------------------------------------------------
// Concat + prescale attention biases; ALSO finishes sigma (phase 3).
// ---------------------------------------------------------------------------
__global__ __launch_bounds__(256)
void concat_bias(const float* __restrict__ qb1, const float* __restrict__ kb1,
                 const float* __restrict__ qb2, const float* __restrict__ kb2,
                 float* __restrict__ bb,
                 const float* __restrict__ S1, const float* __restrict__ S2,
                 float* __restrict__ sig) {
    int t = threadIdx.x;
    if (t < 32) bb[t] = qb1[t] * LOG2E;
    else if (t < 64) bb[t] = kb1[t - 32];
    else if (t < 128) bb[t] = qb2[t - 64] * LOG2E;
    else if (t < 192) bb[t] = kb2[t - 128];
    else if (t >= 224 && t < 229) {
        int L = t - 224;
        float rinv = 1.f / (sqrtf(S1[L]) + 1e-12f);
        float ns2 = rinv * rinv * S2[L];
        float sg = ns2 / (sqrtf(ns2) + 1e-12f);
        sig[L] = 1.f / sg;
    }
}

// ---------------------------------------------------------------------------
// L1 only: fp32 VALU conv (C=6). x (B,C,N) -> out (B,O,N) fp32.
// ---------------------------------------------------------------------------
__global__ __launch_bounds__(256)
void conv_f32_kernel(const float* __restrict__ x, const float* __restrict__ W,
                     const float* __restrict__ bias, const float* __restrict__ sig,
                     float* __restrict__ out, int C, int O, int lrelu) {
    __shared__ float Ws[16][68];
    __shared__ float Xs[16][68];
    int t = threadIdx.x;
    int tx = t & 15, ty = t >> 4;
    int b = blockIdx.z;
    int n0 = blockIdx.x * 64, o0 = blockIdx.y * 64;
    float acc[4][4] = {};
    const float* xb = x + (size_t)b * C * N_PIX;
    for (int c0 = 0; c0 < C; c0 += 16) {
        #pragma unroll
        for (int i = 0; i < 4; ++i) {
            int e = t + i * 256;
            int o = e >> 4, c = e & 15;
            float wv = 0.f;
            if (o0 + o < O && c0 + c < C) wv = W[(size_t)(o0 + o) * C + c0 + c];
            Ws[c][o] = wv;
        }
        #pragma unroll
        for (int i = 0; i < 4; ++i) {
            int e = t + i * 256;
            int c = e >> 6, n = e & 63;
            float xv = 0.f;
            if (c0 + c < C) xv = xb[(size_t)(c0 + c) * N_PIX + n0 + n];
            Xs[c][n] = xv;
        }
        __syncthreads();
        #pragma unroll
        for (int cc = 0; cc < 16; ++cc) {
            float4 wv = *(const float4*)&Ws[cc][ty * 4];
            float4 xv = *(const float4*)&Xs[cc][tx * 4];
            float wa[4] = {wv.x, wv.y, wv.z, wv.w};
            float xa[4] = {xv.x, xv.y, xv.z, xv.w};
            #pragma unroll
            for (int i = 0; i < 4; ++i)
                #pragma unroll
                for (int j = 0; j < 4; ++j)
                    acc[i][j] += wa[i] * xa[j];
        }
        __syncthreads();
    }
    float ivv = sig ? sig[0] : 1.f;
    for (int i = 0; i < 4; ++i) {
        int o = o0 + ty * 4 + i;
        if (o >= O) break;
        float bv = bias[o];
        float vres[4];
        #pragma unroll
        for (int j = 0; j < 4; ++j) {
            float v = acc[i][j] * ivv + bv;
            if (lrelu) v = (v > 0.f) ? v : 0.1f * v;
            vres[j] = v;
        }
        *(float4*)&out[((size_t)b * O + o) * N_PIX + n0 + tx * 4] =
            make_float4(vres[0], vres[1], vres[2], vres[3]);
    }
}

// ---------------------------------------------------------------------------
// Transpose+split: (B,64,N) fp32 -> (B,N,128) bf16 [hi(64)|lo(64)].
// ---------------------------------------------------------------------------
__global__ __launch_bounds__(256)
void tsplit64_kernel(const float* __restrict__ in, __bf16* __restrict__ out) {
    __shared__ float tile[64 * 65];
    int t = threadIdx.x;
    int n0 = blockIdx.x * 64, b = blockIdx.y;
    for (int e = t; e < 64 * 64; e += 256) {
        int c = e >> 6, n = e & 63;
        tile[n * 65 + c] = in[((size_t)b * 64 + c) * N_PIX + n0 + n];
    }
    __syncthreads();
    for (int e = t; e < 64 * 64; e += 256) {
        int n = e >> 6, c = e & 63;
        float v = tile[n * 65 + c];
        __bf16 hi = (__bf16)v;
        size_t base = ((size_t)b * N_PIX + n0 + n) * 128;
        out[base + c] = hi;
        out[base + 64 + c] = (__bf16)(v - (float)hi);
    }
}

// ---------------------------------------------------------------------------
// Split-bf16 MFMA 1x1 conv. MF = m-frags per wave (1 or 2).
// MODE 1 emits fp8-e4m3 (B,O,N) for the attention V buffers.
// ---------------------------------------------------------------------------
template <int WO, int WN, int MF, int MODE, int IN_F32, int LRELU>
__global__ __launch_bounds__(256)
void mfma_conv(const void* __restrict__ xt, const __bf16* __restrict__ wsp,
               const float* __restrict__ bias, float bscale,
               void* __restrict__ outp, int C, int O) {
    constexpr int NT_BLK = WN * 128;
    constexpr int OT_BLK = WO * 16 * MF;
    __shared__ __bf16 Ws[OT_BLK * 72];
    __shared__ __bf16 Xs[NT_BLK * 72];
    int t = threadIdx.x;
    int lane = t & 63, w = t >> 6;
    int l15 = lane & 15, quad = lane >> 4;
    int wo = w / WN, wn = w % WN;
    int b = blockIdx.z;
    int n0b = blockIdx.x * NT_BLK, o0b = blockIdx.y * OT_BLK;

    f32x4 acc[MF][8] = {};

    for (int c0 = 0; c0 < C; c0 += 32) {
        __syncthreads();
        for (int e = t; e < OT_BLK * 8; e += 256) {
            int row = e >> 3, part = e & 7;
            size_t src = (size_t)(o0b + row) * 2 * C +
                         (part < 4 ? c0 + part * 8 : C + c0 + (part - 4) * 8);
            int dst = row * 72 + (part < 4 ? part * 8 : 32 + (part - 4) * 8);
            *(uint4*)&Ws[dst] = *(const uint4*)&wsp[src];
        }
        if (IN_F32) {
            const float* xf = (const float*)xt;
            for (int e = t; e < NT_BLK * 8; e += 256) {
                int row = e >> 3, part = e & 7;
                float4 v = *(const float4*)&xf[((size_t)b * N_PIX + n0b + row) * C + c0 + part * 4];
                bf16x4v hi, lo;
                float va[4] = {v.x, v.y, v.z, v.w};
                #pragma unroll
                for (int j = 0; j < 4; ++j) {
                    hi[j] = (__bf16)va[j];
                    lo[j] = (__bf16)(va[j] - (float)hi[j]);
                }
                *(bf16x4v*)&Xs[row * 72 + part * 4] = hi;
                *(bf16x4v*)&Xs[row * 72 + 32 + part * 4] = lo;
            }
        } else {
            const __bf16* xb = (const __bf16*)xt;
            for (int e = t; e < NT_BLK * 8; e += 256) {
                int row = e >> 3, part = e & 7;
                size_t src = ((size_t)b * N_PIX + n0b + row) * 2 * C +
                             (part < 4 ? c0 + part * 8 : C + c0 + (part - 4) * 8);
                int dst = row * 72 + (part < 4 ? part * 8 : 32 + (part - 4) * 8);
                *(uint4*)&Xs[dst] = *(const uint4*)&xb[src];
            }
        }
        __syncthreads();

        bf16x8 ah[MF], al[MF];
        #pragma unroll
        for (int mf = 0; mf < MF; ++mf) {
            int base = (wo * 16 * MF + mf * 16 + l15) * 72 + quad * 8;
            ah[mf] = *(const bf16x8*)&Ws[base];
            al[mf] = *(const bf16x8*)&Ws[base + 32];
        }
        #pragma unroll
        for (int nt = 0; nt < 8; ++nt) {
            int bbase = (wn * 128 + nt * 16 + l15) * 72 + quad * 8;
            bf16x8 bh = *(const bf16x8*)&Xs[bbase];
            bf16x8 bl = *(const bf16x8*)&Xs[bbase + 32];
            #pragma unroll
            for (int mf = 0; mf < MF; ++mf) {
                acc[mf][nt] = __builtin_amdgcn_mfma_f32_16x16x32_bf16(ah[mf], bh, acc[mf][nt], 0, 0, 0);
                acc[mf][nt] = __builtin_amdgcn_mfma_f32_16x16x32_bf16(ah[mf], bl, acc[mf][nt], 0, 0, 0);
                acc[mf][nt] = __builtin_amdgcn_mfma_f32_16x16x32_bf16(al[mf], bh, acc[mf][nt], 0, 0, 0);
            }
        }
    }

    float bv[MF][4];
    #pragma unroll
    for (int mf = 0; mf < MF; ++mf)
        #pragma unroll
        for (int r = 0; r < 4; ++r)
            bv[mf][r] = bias[o0b + wo * 16 * MF + mf * 16 + quad * 4 + r] * bscale;

    #pragma unroll
    for (int mf = 0; mf < MF; ++mf)
        #pragma unroll
        for (int nt = 0; nt < 8; ++nt) {
            int n = n0b + wn * 128 + nt * 16 + l15;
            float val[4];
            #pragma unroll
            for (int r = 0; r < 4; ++r) {
                float v = acc[mf][nt][r] + bv[mf][r];
                if (LRELU) v = (v > 0.f) ? v : 0.1f * v;
                val[r] = v;
            }
            int obase = o0b + wo * 16 * MF + mf * 16 + quad * 4;
            if (MODE == 1) {  // fp8 (B,O,N) for attention V
                uint8_t* ob = (uint8_t*)outp;
                #pragma unroll
                for (int r = 0; r < 4; ++r)
                    ob[((size_t)b * O + obase + r) * N_PIX + n] = to_fp8(val[r]);
            } else if (MODE == 2) {
                __bf16* ob = (__bf16*)outp;
                bf16x4v hv, lv;
                #pragma unroll
                for (int r = 0; r < 4; ++r) {
                    hv[r] = (__bf16)val[r];
                    lv[r] = (__bf16)(val[r] - (float)hv[r]);
                }
                size_t rb = ((size_t)b * N_PIX + n) * 2 * O + obase;
                *(bf16x4v*)&ob[rb] = hv;
                *(bf16x4v*)&ob[rb + O] = lv;
            } else {  // MODE 4
                __bf16* ob = (__bf16*)outp;
                bf16x4v hv;
                #pragma unroll
                for (int r = 0; r < 4; ++r) hv[r] = (__bf16)val[r];
                *(bf16x4v*)&ob[((size_t)b * N_PIX + n) * O + obase] = hv;
            }
        }
}

// ---------------------------------------------------------------------------
// Attention kernel 1/2: E = exp2(qk-dot) -> FP8-e4m3.
// k-loop restructure (round 8): q fragments loaded once, reused across
// KITER k-tiles; nt-outer accumulation keeps acc at 8 VGPR.
// ---------------------------------------------------------------------------
template <int CQ, int KITER>
__global__ __launch_bounds__(256)
void s_gemm2(const __bf16* __restrict__ qt, const __bf16* __restrict__ kt,
             uint8_t* __restrict__ S, int QSTR) {
    constexpr int NKK = CQ / 32;
    __shared__ uint8_t Ss[128 * 144];
    int t = threadIdx.x;
    int lane = t & 63, w = t >> 6;
    int l15 = lane & 15, quad = lane >> 4;
    int kbase = blockIdx.x * KITER * 128, q0 = blockIdx.y * 128, b = blockIdx.z;

    bf16x8 qf[8][NKK];
    #pragma unroll
    for (int nt = 0; nt < 8; ++nt)
        #pragma unroll
        for (int kk = 0; kk < NKK; ++kk)
            qf[nt][kk] = *(const bf16x8*)&qt[((size_t)b * N_PIX + q0 + nt * 16 + l15) * QSTR + kk * 32 + quad * 8];

    for (int ki = 0; ki < KITER; ++ki) {
        int k0 = kbase + ki * 128;
        bf16x8 kf[2][NKK];
        #pragma unroll
        for (int mf = 0; mf < 2; ++mf)
            #pragma unroll
            for (int kk = 0; kk < NKK; ++kk)
                kf[mf][kk] = *(const bf16x8*)&kt[((size_t)b * N_PIX + k0 + w * 32 + mf * 16 + l15) * QSTR + kk * 32 + quad * 8];

        #pragma unroll
        for (int nt = 0; nt < 8; ++nt) {
            f32x4 a[2] = {};
            #pragma unroll
            for (int kk = 0; kk < NKK; ++kk)
                #pragma unroll
                for (int mf = 0; mf < 2; ++mf)
                    a[mf] = __builtin_amdgcn_mfma_f32_16x16x32_bf16(kf[mf][kk], qf[nt][kk], a[mf], 0, 0, 0);
            #pragma unroll
            for (int mf = 0; mf < 2; ++mf) {
                unsigned p = pack4_fp8(exp2f(a[mf][0]), exp2f(a[mf][1]),
                                       exp2f(a[mf][2]), exp2f(a[mf][3]));
                *(unsigned*)&Ss[(nt * 16 + l15) * 144 + w * 32 + mf * 16 + quad * 4] = p;
            }
        }
        __syncthreads();
        // coalesced fp8 write (64B per thread per row-half)
        int ql = t >> 1, kh = (t & 1) * 64;
        size_t row = ((size_t)b * N_PIX + q0 + ql) * (size_t)N_PIX + k0 + kh;
        #pragma unroll
        for (int j = 0; j < 4; ++j)
            *(uint4*)&S[row + j * 16] = *(const uint4*)&Ss[ql * 144 + kh + j * 16];
        __syncthreads();  // Ss reused next iteration
    }
}

// ---------------------------------------------------------------------------
// Attention kernel 2/2: FP8 PV GEMM, QROWSxCCH tile, 1024 threads/16 waves.
// Round 9: depth-3 pipeline with counted vmcnt (T3+T4), retried now that
// it costs ZERO occupancy: pv already runs 1 block/CU (98KB LDS, grid=256
// = 1/CU), so the 3rd buffer set (147KB attn2 / 96KB attn1, <=160KB) is
// free.  Round-3's regression was the 3->2 blocks/CU cliff at the 128 tile
// -- that confound is absent here.
// Schedule per tile t (round-3-verified step structure):
//   wait  s_waitcnt vmcnt(NLOADS) lgkmcnt(0)   (tile t's loads done,
//         tile t+1's NLOADS still in flight; never drains to 0 in-loop)
//   s_barrier (sched_barrier-fenced)           (cross-wave: all waves'
//         tile-t loads retired -> LDS complete)
//   stage(t+2)  (buffer (t+2)%3 == (t-1)%3: safe, compute(t-1)'s ds_reads
//         all retired before their MFMAs issued, and all waves passed the
//         barrier after compute(t-1))
//   compute(t)
// NLOADS = QROWS/128 + 1 per wave (P chunks + 1 V chunk).
// Softmax denominators in-kernel via ones-MFMA (round 7).
// ---------------------------------------------------------------------------
typedef __attribute__((address_space(1))) const void* gas1_t;
typedef __attribute__((address_space(3))) void* las3_t;

template <int NT, int QROWS>
__global__ __launch_bounds__(1024)
void pv_gemm14(const uint8_t* __restrict__ E, const uint8_t* __restrict__ vg,
               const __bf16* __restrict__ xin2,
               const float* __restrict__ gamma, float* __restrict__ out, int C) {
    constexpr int NQS = QROWS / 32;
    constexpr int NCS = 16 / NQS;
    constexpr int CCH = NT * 16 * NCS;
    constexpr int NPAIR = (N_PIX / QROWS) * BATCH;
    __shared__ uint8_t Psh[3][QROWS * 128];
    __shared__ uint8_t Vsh[3][CCH * 128];
    int t = threadIdx.x;
    int lane = t & 63, w = t >> 6;
    int l15 = lane & 15, quad = lane >> 4;
    int qs = w % NQS, cs = w / NQS;
    int bid = blockIdx.x;
    int pair = bid % NPAIR, cblk = bid / NPAIR;
    int qi = pair >> 2, b = pair & 3;
    int q0 = qi * QROWS, c0 = cblk * CCH;
    const uint8_t* Pb = E + ((size_t)b * N_PIX + q0) * (size_t)N_PIX;
    const uint8_t* Vb = vg + ((size_t)b * C + c0) * (size_t)N_PIX;

    int r8 = lane >> 3;           // row within 8-row chunk
    int cgl = (lane & 7) ^ r8;    // swizzled 16B column group to load

    const long ONES = 0x3838383838383838L;  // 8x fp8-e4m3 1.0

    f32x4 acc[2][NT] = {};
    f32x4 acc_s[2] = {};          // row-sum accumulators (per-lane own rows)

    auto stage = [&](int s, int k0t) {
        uint8_t* Ps = Psh[s];
        uint8_t* Vs = Vsh[s];
        #pragma unroll
        for (int ch = 0; ch < QROWS / 128; ++ch) {
            int row0 = w * (QROWS / 16) + ch * 8;
            const uint8_t* g = Pb + (size_t)(row0 + r8) * N_PIX + k0t + cgl * 16;
            __builtin_amdgcn_global_load_lds((gas1_t)g, (las3_t)&Ps[row0 * 128], 16, 0, 0);
        }
        static_assert(CCH / 8 == 16, "V staging assumes 16 chunks");
        {
            int row0 = w * 8;
            const uint8_t* g = Vb + (size_t)(row0 + r8) * N_PIX + k0t + cgl * 16;
            __builtin_amdgcn_global_load_lds((gas1_t)g, (las3_t)&Vs[row0 * 128], 16, 0, 0);
        }
    };

    // XOR cg swizzle, phase-minimal bank pattern
    auto compute = [&](int s) {
        const uint8_t* Ps = Psh[s];
        const uint8_t* Vs = Vsh[s];
        #pragma unroll
        for (int kk = 0; kk < 4; ++kk) {
            long pa[2];
            #pragma unroll
            for (int mf = 0; mf < 2; ++mf) {
                int row = qs * 32 + mf * 16 + l15;
                int cg = (2 * kk + (quad >> 1)) ^ (row & 7);
                pa[mf] = *(const long*)&Ps[row * 128 + cg * 16 + (quad & 1) * 8];
            }
            #pragma unroll
            for (int mf = 0; mf < 2; ++mf)
                acc_s[mf] = __builtin_amdgcn_mfma_f32_16x16x32_fp8_fp8(pa[mf], ONES, acc_s[mf], 0, 0, 0);
            #pragma unroll
            for (int nt = 0; nt < NT; ++nt) {
                int row = cs * (NT * 16) + nt * 16 + l15;
                int cg = (2 * kk + (quad >> 1)) ^ (row & 7);
                long vf = *(const long*)&Vs[row * 128 + cg * 16 + (quad & 1) * 8];
                #pragma unroll
                for (int mf = 0; mf < 2; ++mf)
                    acc[mf][nt] = __builtin_amdgcn_mfma_f32_16x16x32_fp8_fp8(pa[mf], vf, acc[mf][nt], 0, 0, 0);
            }
        }
    };

    // steady-state wait: oldest in-flight stage done, next stage's NLOADS
    // (= QROWS/128 + 1 per wave) still in flight.
    auto wait_steady = [&] {
        if constexpr (QROWS == 256)
            asm volatile("s_waitcnt vmcnt(3) lgkmcnt(0)" ::: "memory");
        else
            asm volatile("s_waitcnt vmcnt(2) lgkmcnt(0)" ::: "memory");
    };

    auto step = [&](int s, int k0t) {   // s, (s+2)%3 constant-fold at call sites
        wait_steady();
        __builtin_amdgcn_sched_barrier(0);
        __builtin_amdgcn_s_barrier();
        __builtin_amdgcn_sched_barrier(0);
        stage((s + 2) % 3, k0t + 256);
        __builtin_amdgcn_sched_barrier(0);
        compute(s);
    };

    stage(0, 0);
    stage(1, 128);

    int k0 = 0;
    for (int r = 0; r < 10; ++r) {   // computes tiles 0..29 (stages reach 31)
        step(0, k0);
        step(1, k0 + 128);
        step(2, k0 + 256);
        k0 += 384;
    }
    // tile 30 (buf 0): tile 31's loads stay in flight
    wait_steady();
    __builtin_amdgcn_sched_barrier(0);
    __builtin_amdgcn_s_barrier();
    __builtin_amdgcn_sched_barrier(0);
    compute(0);
    // tile 31 (buf 1): last tile -> full drain
    asm volatile("s_waitcnt vmcnt(0) lgkmcnt(0)" ::: "memory");
    __builtin_amdgcn_sched_barrier(0);
    __builtin_amdgcn_s_barrier();
    __builtin_amdgcn_sched_barrier(0);
    compute(1);

    float g = gamma[0];
    #pragma unroll
    for (int mf = 0; mf < 2; ++mf)
        #pragma unroll
        for (int r = 0; r < 4; ++r) {
            int ql = qs * 32 + mf * 16 + quad * 4 + r;
            int q = q0 + ql;
            float gil = g / acc_s[mf][r];
            size_t xrb = ((size_t)b * N_PIX + q) * 2 * C;
            size_t orb = ((size_t)b * N_PIX + q) * C;
            #pragma unroll
            for (int nt = 0; nt < NT; ++nt) {
                int c = c0 + cs * (NT * 16) + nt * 16 + l15;
                float xr = (float)xin2[xrb + c] + (float)xin2[xrb + C + c];
                out[orb + c] = gil * acc[mf][nt][r] + xr;
            }
        }
}

// ---------------------------------------------------------------------------
// L5: out[b,n] = lrelu(iv * dot(W5, h[b,n,:]) + b5).  h: (B,N,512) fp32.
// ---------------------------------------------------------------------------
__global__ __launch_bounds__(256)
void l5_kernel(const float* __restrict__ h, const float* __restrict__ W5,
               const float* __restrict__ b5, const float* __restrict__ sig,
               float* __restrict__ out) {
    int t = threadIdx.x;
    int lane = t & 63, w = t >> 6;
    int p = blockIdx.x * 4 + w;
    const float* row = h + (size_t)p * 512;
    float4 a0 = *(const float4*)&row[lane * 8];
    float4 a1 = *(const float4*)&row[lane * 8 + 4];
    float4 w0 = *(const float4*)&W5[lane * 8];
    float4 w1 = *(const float4*)&W5[lane * 8 + 4];
    float s = a0.x * w0.x + a0.y * w0.y + a0.z * w0.z + a0.w * w0.w +
              a1.x * w1.x + a1.y * w1.y + a1.z * w1.z + a1.w * w1.w;
    #pragma unroll
    for (int off = 1; off < 64; off <<= 1) s += __shfl_xor(s, off);
    if (lane == 0) {
        float v = sig[0] * s + b5[0];
        out[p] = (v > 0.f) ? v : 0.1f * v;
    }
}

// ---------------------------------------------------------------------------
// Launcher
// ---------------------------------------------------------------------------
extern "C" void kernel_launch(void* const* d_in, const int* in_sizes, int n_in,
                              void* d_out, int out_size, void* d_ws, size_t ws_size,
                              hipStream_t stream) {
    const float* x   = (const float*)d_in[0];
    const float* W1  = (const float*)d_in[1];
    const float* b1  = (const float*)d_in[2];
    const float* u1  = (const float*)d_in[3];
    const float* W2  = (const float*)d_in[4];
    const float* b2  = (const float*)d_in[5];
    const float* u2  = (const float*)d_in[6];
    const float* W3  = (const float*)d_in[7];
    const float* b3  = (const float*)d_in[8];
    const float* u3  = (const float*)d_in[9];
    const float* W4  = (const float*)d_in[10];
    const float* b4  = (const float*)d_in[11];
    const float* u4  = (const float*)d_in[12];
    const float* W5  = (const float*)d_in[13];
    const float* b5  = (const float*)d_in[14];
    const float* u5  = (const float*)d_in[15];
    const float* a1_qW = (const float*)d_in[16];
    const float* a1_qb = (const float*)d_in[17];
    const float* a1_kW = (const float*)d_in[18];
    const float* a1_kb = (const float*)d_in[19];
    const float* a1_vW = (const float*)d_in[20];
    const float* a1_vb = (const float*)d_in[21];
    const float* a1_g  = (const float*)d_in[22];
    const float* a2_qW = (const float*)d_in[23];
    const float* a2_qb = (const float*)d_in[24];
    const float* a2_kW = (const float*)d_in[25];
    const float* a2_kb = (const float*)d_in[26];
    const float* a2_vW = (const float*)d_in[27];
    const float* a2_vb = (const float*)d_in[28];
    const float* a2_g  = (const float*)d_in[29];

    float* ws = (float*)d_ws;
    const size_t NF = (size_t)BATCH * N_PIX;  // 16384
    float* sig    = ws;                       // 16
    float* h1     = ws + 16;                  // NF*64 fl
    float* slabC  = h1 + NF * 64;             // NF*512 fl
    float* slabS1 = slabC + NF * 512;         // NF*256 fl
    float* slabS2 = slabS1 + NF * 256;        // NF*512 fl
    float* qtf    = slabS2 + NF * 512;        // NF*32 fl
    float* ktf    = qtf + NF * 32;            // NF*32 fl
    float* wspf   = ktf + NF * 32;            // ~0.58M fl weights
    float* bbf    = wspf + 592000;            // 192 fl bias concat
    float* ysig   = wspf + 592256;            // sigma scratch: y[5*512]+S1[5]+S2[5]
    float* Sf     = wspf + 600000;            // E: NF*4096 fp8 bytes

    __bf16* h1t = (__bf16*)slabS1;            // (B,N,128)
    __bf16* h2t = (__bf16*)slabS2;            // (B,N,256)
    __bf16* h3t = (__bf16*)slabS1;            // (B,N,512)
    __bf16* h5t = (__bf16*)slabS2;            // (B,N,1024)
    float*  h4t = slabC;                      // (B,N,256) fp32
    uint8_t* vb1 = (uint8_t*)(slabC + NF * 256);  // (B,256,N) fp8
    float*  h6t = slabC;                      // (B,N,512) fp32
    uint8_t* vb2 = (uint8_t*)slabS1;          // (B,512,N) fp8
    __bf16* qkt = (__bf16*)qtf;               // (B,N,2CQ) packed [q|k]
    __bf16* wsp = (__bf16*)wspf;
    uint8_t* Sbuf = (uint8_t*)Sf;             // (B,4096,4096) fp8

    float* ybuf = ysig;                       // 5*512
    float* S1v  = ysig + 2560;                // 5 (16-aligned pad below)
    float* S2v  = ysig + 2576;                // 5

    __bf16* wsL2  = wsp;            // 128*128
    __bf16* wsL3  = wsL2 + 16384;   // 256*256
    __bf16* wsL4  = wsL3 + 65536;   // 512*512
    __bf16* wsA1q = wsL4 + 262144;  // 32*512   [combined with wsA1k]
    __bf16* wsA1k = wsA1q + 16384;
    __bf16* wsA1v = wsA1k + 16384;  // 256*512
    __bf16* wsA2q = wsA1v + 131072; // 64*1024  [combined with wsA2k]
    __bf16* wsA2k = wsA2q + 65536;
    __bf16* wsA2v = wsA2k + 65536;  // 512*1024

    dim3 blk(256);

    SigP sp;
    sp.W[0] = W1; sp.u[0] = u1; sp.O[0] = 64;  sp.C[0] = 6;
    sp.W[1] = W2; sp.u[1] = u2; sp.O[1] = 128; sp.C[1] = 64;
    sp.W[2] = W3; sp.u[2] = u3; sp.O[2] = 256; sp.C[2] = 128;
    sp.W[3] = W4; sp.u[3] = u4; sp.O[3] = 512; sp.C[3] = 256;
    sp.W[4] = W5; sp.u[4] = u5; sp.O[4] = 1;   sp.C[4] = 512;

    hipMemsetAsync(ysig, 0, 2592 * sizeof(float), stream);
    sigma_p1<<<dim3(16), blk, 0, stream>>>(sp, ybuf);
    sigma_p2<<<dim3(16), blk, 0, stream>>>(sp, ybuf, S1v, S2v);
    concat_bias<<<1, blk, 0, stream>>>(a1_qb, a1_kb, a2_qb, a2_kb, bbf, S1v, S2v, sig);

    wsplit_kernel<<<128, blk, 0, stream>>>(W2, sig + 1, 1.f, 64, wsL2);
    wsplit_kernel<<<256, blk, 0, stream>>>(W3, sig + 2, 1.f, 128, wsL3);
    wsplit_kernel<<<512, blk, 0, stream>>>(W4, sig + 3, 1.f, 256, wsL4);
    wsplit_kernel<<<32,  blk, 0, stream>>>(a1_qW, nullptr, LOG2E, 256, wsA1q);
    wsplit_kernel<<<32,  blk, 0, stream>>>(a1_kW, nullptr, 1.f, 256, wsA1k);
    wsplit_kernel<<<256, blk, 0, stream>>>(a1_vW, nullptr, 1.f, 256, wsA1v);
    wsplit_kernel<<<64,  blk, 0, stream>>>(a2_qW, nullptr, LOG2E, 512, wsA2q);
    wsplit_kernel<<<64,  blk, 0, stream>>>(a2_kW, nullptr, 1.f, 512, wsA2k);
    wsplit_kernel<<<512, blk, 0, stream>>>(a2_vW, nullptr, 1.f, 512, wsA2v);

    // L1 (fp32) + transpose/split
    conv_f32_kernel<<<dim3(64, 1, 4), blk, 0, stream>>>(x, W1, b1, sig + 0, h1, 6, 64, 1);
    tsplit64_kernel<<<dim3(64, 4), blk, 0, stream>>>(h1, h1t);

    // L2, L3 (split-MFMA, MF=1)
    mfma_conv<4, 1, 1, 2, 0, 1><<<dim3(32, 2, 4), blk, 0, stream>>>(h1t, wsL2, b2, 1.f, h2t, 64, 128);
    mfma_conv<4, 1, 1, 2, 0, 1><<<dim3(32, 4, 4), blk, 0, stream>>>(h2t, wsL3, b3, 1.f, h3t, 128, 256);

    // attention 1 (C=256, Cq=32)
    mfma_conv<2, 2, 1, 4, 0, 0><<<dim3(16, 2, 4), blk, 0, stream>>>(h3t, wsA1q, bbf, 1.f, qkt, 256, 64);
    mfma_conv<4, 1, 1, 1, 0, 0><<<dim3(32, 4, 4), blk, 0, stream>>>(h3t, wsA1v, a1_vb, 1.f, vb1, 256, 256);
    s_gemm2<32, 4><<<dim3(8, 32, 4), blk, 0, stream>>>(qkt, qkt + 32, Sbuf, 64);
    pv_gemm14<2, 128><<<dim3(256), dim3(1024), 0, stream>>>(Sbuf, vb1, h3t, a1_g, h4t, 256);

    // L4 (fp32-transposed input)
    mfma_conv<4, 1, 1, 2, 1, 1><<<dim3(32, 8, 4), blk, 0, stream>>>(h4t, wsL4, b4, 1.f, h5t, 256, 512);

    // attention 2 (C=512, Cq=64)
    mfma_conv<2, 2, 1, 4, 0, 0><<<dim3(16, 4, 4), blk, 0, stream>>>(h5t, wsA2q, bbf + 64, 1.f, qkt, 512, 128);
    mfma_conv<4, 1, 1, 1, 0, 0><<<dim3(32, 8, 4), blk, 0, stream>>>(h5t, wsA2v, a2_vb, 1.f, vb2, 512, 512);
    s_gemm2<64, 4><<<dim3(8, 32, 4), blk, 0, stream>>>(qkt, qkt + 64, Sbuf, 128);
    pv_gemm14<4, 256><<<dim3(256), dim3(1024), 0, stream>>>(Sbuf, vb2, h5t, a2_g, h6t, 512);

    // L5
    l5_kernel<<<4096, blk, 0, stream>>>(h6t, W5, b5, sig + 4, (float*)d_out);
}

// Round 10
// 526.357 us; speedup vs baseline: 1.0252x; 1.0252x over previous
//
#include <hip/hip_runtime.h>
#include <math.h>

#define N_PIX 4096  // H*W = 64*64
#define BATCH 4
#define LOG2E 1.4426950408889634f

typedef __bf16 bf16x8 __attribute__((ext_vector_type(8)));
typedef __bf16 bf16x4v __attribute__((ext_vector_type(4)));
typedef float f32x4 __attribute__((ext_vector_type(4)));

// fp8 e4m3 (OCP on gfx950) pack/unpack via HW cvt builtins
__device__ __forceinline__ unsigned pack4_fp8(float a, float b, float c, float d) {
    unsigned p = __builtin_amdgcn_cvt_pk_fp8_f32(a, b, 0, false);
    p = __builtin_amdgcn_cvt_pk_fp8_f32(c, d, p, true);
    return p;
}
__device__ __forceinline__ uint8_t to_fp8(float v) {
    return (uint8_t)(__builtin_amdgcn_cvt_pk_fp8_f32(v, v, 0, false) & 0xff);
}

// ---------------------------------------------------------------------------
// Spectral norm, parallel 3-phase version.
// sigma = ||W (W^T u)|| / ||W^T u||  (intermediate normalization cancels).
// ---------------------------------------------------------------------------
struct SigP {
    const float* W[5];
    const float* u[5];
    int O[5];
    int C[5];
};

// block -> (layer, 64-row chunk): counts {1,2,4,8,1}
__device__ __forceinline__ void sig_map(int bid, int& L, int& ch) {
    if (bid == 0)      { L = 0; ch = 0; }
    else if (bid < 3)  { L = 1; ch = bid - 1; }
    else if (bid < 7)  { L = 2; ch = bid - 3; }
    else if (bid < 15) { L = 3; ch = bid - 7; }
    else               { L = 4; ch = 0; }
}

__global__ __launch_bounds__(256)
void sigma_p1(SigP p, float* __restrict__ ybuf) {
    __shared__ float ush[64];
    int L, ch;
    sig_map(blockIdx.x, L, ch);
    const float* W = p.W[L];
    const float* u = p.u[L];
    int O = p.O[L], C = p.C[L];
    int o0 = ch * 64;
    int no = O - o0; if (no > 64) no = 64;
    int t = threadIdx.x;
    if (t < 64) ush[t] = (t < no) ? u[o0 + t] : 0.f;
    __syncthreads();
    for (int c = t; c < C; c += 256) {
        float a = 0.f;
        for (int o = 0; o < no; ++o) a += W[(size_t)(o0 + o) * C + c] * ush[o];
        atomicAdd(&ybuf[L * 512 + c], a);
    }
}

__global__ __launch_bounds__(256)
void sigma_p2(SigP p, const float* __restrict__ ybuf,
              float* __restrict__ S1, float* __restrict__ S2) {
    __shared__ float ysh[512];
    int L, ch;
    sig_map(blockIdx.x, L, ch);
    const float* W = p.W[L];
    int O = p.O[L], C = p.C[L];
    int o0 = ch * 64;
    int o_hi = o0 + 64; if (o_hi > O) o_hi = O;
    int t = threadIdx.x;
    int lane = t & 63, w = t >> 6;
    for (int c = t; c < C; c += 256) ysh[c] = ybuf[L * 512 + c];
    __syncthreads();

    if (ch == 0) {
        float s = 0.f;
        for (int c = t; c < C; c += 256) s += ysh[c] * ysh[c];
        #pragma unroll
        for (int off = 1; off < 64; off <<= 1) s += __shfl_xor(s, off);
        if (lane == 0) atomicAdd(&S1[L], s);
    }

    float sq = 0.f;
    for (int i = 0; i < 16; ++i) {
        int o = o0 + w * 16 + i;
        if (o >= o_hi) break;
        float a = 0.f;
        for (int c = lane; c < C; c += 64) a += W[(size_t)o * C + c] * ysh[c];
        #pragma unroll
        for (int off = 1; off < 64; off <<= 1) a += __shfl_xor(a, off);
        if (lane == 0) sq += a * a;
    }
    if (lane == 0) atomicAdd(&S2[L], sq);
}

// ---------------------------------------------------------------------------
// Weight split: (O,C) fp32 * iv * scale -> (O, 2C) bf16  [hi | lo].
// ---------------------------------------------------------------------------
__global__ __launch_bounds__(256)
void wsplit_kernel(const float* __restrict__ W, const float* __restrict__ iv,
                   float scale, int C, __bf16* __restrict__ out) {
    int o = blockIdx.x;
    float s = (iv ? iv[0] : 1.f) * scale;
    for (int c = threadIdx.x; c < C; c += 256) {
        float wv = W[(size_t)o * C + c] * s;
        __bf16 hi = (__bf16)wv;
        float lo = wv - (float)hi;
        out[(size_t)o * 2 * C + c] = hi;
        out[(size_t)o * 2 * C + C + c] = (__bf16)lo;
    }
}

// ---------------------------------------------------------------------------
// Concat + prescale attention biases; ALSO finishes sigma (phase 3).
// ---------------------------------------------------------------------------
__global__ __launch_bounds__(256)
void concat_bias(const float* __restrict__ qb1, const float* __restrict__ kb1,
                 const float* __restrict__ qb2, const float* __restrict__ kb2,
                 float* __restrict__ bb,
                 const float* __restrict__ S1, const float* __restrict__ S2,
                 float* __restrict__ sig) {
    int t = threadIdx.x;
    if (t < 32) bb[t] = qb1[t] * LOG2E;
    else if (t < 64) bb[t] = kb1[t - 32];
    else if (t < 128) bb[t] = qb2[t - 64] * LOG2E;
    else if (t < 192) bb[t] = kb2[t - 128];
    else if (t >= 224 && t < 229) {
        int L = t - 224;
        float rinv = 1.f / (sqrtf(S1[L]) + 1e-12f);
        float ns2 = rinv * rinv * S2[L];
        float sg = ns2 / (sqrtf(ns2) + 1e-12f);
        sig[L] = 1.f / sg;
    }
}

// ---------------------------------------------------------------------------
// L1 only: fp32 VALU conv (C=6). x (B,C,N) -> out (B,O,N) fp32.
// ---------------------------------------------------------------------------
__global__ __launch_bounds__(256)
void conv_f32_kernel(const float* __restrict__ x, const float* __restrict__ W,
                     const float* __restrict__ bias, const float* __restrict__ sig,
                     float* __restrict__ out, int C, int O, int lrelu) {
    __shared__ float Ws[16][68];
    __shared__ float Xs[16][68];
    int t = threadIdx.x;
    int tx = t & 15, ty = t >> 4;
    int b = blockIdx.z;
    int n0 = blockIdx.x * 64, o0 = blockIdx.y * 64;
    float acc[4][4] = {};
    const float* xb = x + (size_t)b * C * N_PIX;
    for (int c0 = 0; c0 < C; c0 += 16) {
        #pragma unroll
        for (int i = 0; i < 4; ++i) {
            int e = t + i * 256;
            int o = e >> 4, c = e & 15;
            float wv = 0.f;
            if (o0 + o < O && c0 + c < C) wv = W[(size_t)(o0 + o) * C + c0 + c];
            Ws[c][o] = wv;
        }
        #pragma unroll
        for (int i = 0; i < 4; ++i) {
            int e = t + i * 256;
            int c = e >> 6, n = e & 63;
            float xv = 0.f;
            if (c0 + c < C) xv = xb[(size_t)(c0 + c) * N_PIX + n0 + n];
            Xs[c][n] = xv;
        }
        __syncthreads();
        #pragma unroll
        for (int cc = 0; cc < 16; ++cc) {
            float4 wv = *(const float4*)&Ws[cc][ty * 4];
            float4 xv = *(const float4*)&Xs[cc][tx * 4];
            float wa[4] = {wv.x, wv.y, wv.z, wv.w};
            float xa[4] = {xv.x, xv.y, xv.z, xv.w};
            #pragma unroll
            for (int i = 0; i < 4; ++i)
                #pragma unroll
                for (int j = 0; j < 4; ++j)
                    acc[i][j] += wa[i] * xa[j];
        }
        __syncthreads();
    }
    float ivv = sig ? sig[0] : 1.f;
    for (int i = 0; i < 4; ++i) {
        int o = o0 + ty * 4 + i;
        if (o >= O) break;
        float bv = bias[o];
        float vres[4];
        #pragma unroll
        for (int j = 0; j < 4; ++j) {
            float v = acc[i][j] * ivv + bv;
            if (lrelu) v = (v > 0.f) ? v : 0.1f * v;
            vres[j] = v;
        }
        *(float4*)&out[((size_t)b * O + o) * N_PIX + n0 + tx * 4] =
            make_float4(vres[0], vres[1], vres[2], vres[3]);
    }
}

// ---------------------------------------------------------------------------
// Transpose+split: (B,64,N) fp32 -> (B,N,128) bf16 [hi(64)|lo(64)].
// ---------------------------------------------------------------------------
__global__ __launch_bounds__(256)
void tsplit64_kernel(const float* __restrict__ in, __bf16* __restrict__ out) {
    __shared__ float tile[64 * 65];
    int t = threadIdx.x;
    int n0 = blockIdx.x * 64, b = blockIdx.y;
    for (int e = t; e < 64 * 64; e += 256) {
        int c = e >> 6, n = e & 63;
        tile[n * 65 + c] = in[((size_t)b * 64 + c) * N_PIX + n0 + n];
    }
    __syncthreads();
    for (int e = t; e < 64 * 64; e += 256) {
        int n = e >> 6, c = e & 63;
        float v = tile[n * 65 + c];
        __bf16 hi = (__bf16)v;
        size_t base = ((size_t)b * N_PIX + n0 + n) * 128;
        out[base + c] = hi;
        out[base + 64 + c] = (__bf16)(v - (float)hi);
    }
}

// ---------------------------------------------------------------------------
// Split-bf16 MFMA 1x1 conv. MF = m-frags per wave (1 or 2).
// MODE 1 emits fp8-e4m3 (B,O,N) for the attention V buffers.
// ---------------------------------------------------------------------------
template <int WO, int WN, int MF, int MODE, int IN_F32, int LRELU>
__global__ __launch_bounds__(256)
void mfma_conv(const void* __restrict__ xt, const __bf16* __restrict__ wsp,
               const float* __restrict__ bias, float bscale,
               void* __restrict__ outp, int C, int O) {
    constexpr int NT_BLK = WN * 128;
    constexpr int OT_BLK = WO * 16 * MF;
    __shared__ __bf16 Ws[OT_BLK * 72];
    __shared__ __bf16 Xs[NT_BLK * 72];
    int t = threadIdx.x;
    int lane = t & 63, w = t >> 6;
    int l15 = lane & 15, quad = lane >> 4;
    int wo = w / WN, wn = w % WN;
    int b = blockIdx.z;
    int n0b = blockIdx.x * NT_BLK, o0b = blockIdx.y * OT_BLK;

    f32x4 acc[MF][8] = {};

    for (int c0 = 0; c0 < C; c0 += 32) {
        __syncthreads();
        for (int e = t; e < OT_BLK * 8; e += 256) {
            int row = e >> 3, part = e & 7;
            size_t src = (size_t)(o0b + row) * 2 * C +
                         (part < 4 ? c0 + part * 8 : C + c0 + (part - 4) * 8);
            int dst = row * 72 + (part < 4 ? part * 8 : 32 + (part - 4) * 8);
            *(uint4*)&Ws[dst] = *(const uint4*)&wsp[src];
        }
        if (IN_F32) {
            const float* xf = (const float*)xt;
            for (int e = t; e < NT_BLK * 8; e += 256) {
                int row = e >> 3, part = e & 7;
                float4 v = *(const float4*)&xf[((size_t)b * N_PIX + n0b + row) * C + c0 + part * 4];
                bf16x4v hi, lo;
                float va[4] = {v.x, v.y, v.z, v.w};
                #pragma unroll
                for (int j = 0; j < 4; ++j) {
                    hi[j] = (__bf16)va[j];
                    lo[j] = (__bf16)(va[j] - (float)hi[j]);
                }
                *(bf16x4v*)&Xs[row * 72 + part * 4] = hi;
                *(bf16x4v*)&Xs[row * 72 + 32 + part * 4] = lo;
            }
        } else {
            const __bf16* xb = (const __bf16*)xt;
            for (int e = t; e < NT_BLK * 8; e += 256) {
                int row = e >> 3, part = e & 7;
                size_t src = ((size_t)b * N_PIX + n0b + row) * 2 * C +
                             (part < 4 ? c0 + part * 8 : C + c0 + (part - 4) * 8);
                int dst = row * 72 + (part < 4 ? part * 8 : 32 + (part - 4) * 8);
                *(uint4*)&Xs[dst] = *(const uint4*)&xb[src];
            }
        }
        __syncthreads();

        bf16x8 ah[MF], al[MF];
        #pragma unroll
        for (int mf = 0; mf < MF; ++mf) {
            int base = (wo * 16 * MF + mf * 16 + l15) * 72 + quad * 8;
            ah[mf] = *(const bf16x8*)&Ws[base];
            al[mf] = *(const bf16x8*)&Ws[base + 32];
        }
        #pragma unroll
        for (int nt = 0; nt < 8; ++nt) {
            int bbase = (wn * 128 + nt * 16 + l15) * 72 + quad * 8;
            bf16x8 bh = *(const bf16x8*)&Xs[bbase];
            bf16x8 bl = *(const bf16x8*)&Xs[bbase + 32];
            #pragma unroll
            for (int mf = 0; mf < MF; ++mf) {
                acc[mf][nt] = __builtin_amdgcn_mfma_f32_16x16x32_bf16(ah[mf], bh, acc[mf][nt], 0, 0, 0);
                acc[mf][nt] = __builtin_amdgcn_mfma_f32_16x16x32_bf16(ah[mf], bl, acc[mf][nt], 0, 0, 0);
                acc[mf][nt] = __builtin_amdgcn_mfma_f32_16x16x32_bf16(al[mf], bh, acc[mf][nt], 0, 0, 0);
            }
        }
    }

    float bv[MF][4];
    #pragma unroll
    for (int mf = 0; mf < MF; ++mf)
        #pragma unroll
        for (int r = 0; r < 4; ++r)
            bv[mf][r] = bias[o0b + wo * 16 * MF + mf * 16 + quad * 4 + r] * bscale;

    #pragma unroll
    for (int mf = 0; mf < MF; ++mf)
        #pragma unroll
        for (int nt = 0; nt < 8; ++nt) {
            int n = n0b + wn * 128 + nt * 16 + l15;
            float val[4];
            #pragma unroll
            for (int r = 0; r < 4; ++r) {
                float v = acc[mf][nt][r] + bv[mf][r];
                if (LRELU) v = (v > 0.f) ? v : 0.1f * v;
                val[r] = v;
            }
            int obase = o0b + wo * 16 * MF + mf * 16 + quad * 4;
            if (MODE == 1) {  // fp8 (B,O,N) for attention V
                uint8_t* ob = (uint8_t*)outp;
                #pragma unroll
                for (int r = 0; r < 4; ++r)
                    ob[((size_t)b * O + obase + r) * N_PIX + n] = to_fp8(val[r]);
            } else if (MODE == 2) {
                __bf16* ob = (__bf16*)outp;
                bf16x4v hv, lv;
                #pragma unroll
                for (int r = 0; r < 4; ++r) {
                    hv[r] = (__bf16)val[r];
                    lv[r] = (__bf16)(val[r] - (float)hv[r]);
                }
                size_t rb = ((size_t)b * N_PIX + n) * 2 * O + obase;
                *(bf16x4v*)&ob[rb] = hv;
                *(bf16x4v*)&ob[rb + O] = lv;
            } else {  // MODE 4
                __bf16* ob = (__bf16*)outp;
                bf16x4v hv;
                #pragma unroll
                for (int r = 0; r < 4; ++r) hv[r] = (__bf16)val[r];
                *(bf16x4v*)&ob[((size_t)b * N_PIX + n) * O + obase] = hv;
            }
        }
}

// ---------------------------------------------------------------------------
// Attention kernel 1/2: E = exp2(qk-dot) -> FP8-e4m3.
// Round 10: KITER=8 (q fragments amortized over 1024 k-cols) + double-
// buffered Ss so there is ONE __syncthreads per k-tile instead of two.
// Safety of single sync: iter i+2's writes to Ss[cur] happen only after
// barrier i+1, which each thread reaches only after completing its iter-i
// reads of Ss[cur] (program order + lgkmcnt folded into __syncthreads).
// ---------------------------------------------------------------------------
template <int CQ, int KITER>
__global__ __launch_bounds__(256)
void s_gemm3(const __bf16* __restrict__ qt, const __bf16* __restrict__ kt,
             uint8_t* __restrict__ S, int QSTR) {
    constexpr int NKK = CQ / 32;
    __shared__ uint8_t Ss[2][128 * 144];
    int t = threadIdx.x;
    int lane = t & 63, w = t >> 6;
    int l15 = lane & 15, quad = lane >> 4;
    int kbase = blockIdx.x * KITER * 128, q0 = blockIdx.y * 128, b = blockIdx.z;

    bf16x8 qf[8][NKK];
    #pragma unroll
    for (int nt = 0; nt < 8; ++nt)
        #pragma unroll
        for (int kk = 0; kk < NKK; ++kk)
            qf[nt][kk] = *(const bf16x8*)&qt[((size_t)b * N_PIX + q0 + nt * 16 + l15) * QSTR + kk * 32 + quad * 8];

    for (int ki = 0; ki < KITER; ++ki) {
        int k0 = kbase + ki * 128;
        int cur = ki & 1;
        bf16x8 kf[2][NKK];
        #pragma unroll
        for (int mf = 0; mf < 2; ++mf)
            #pragma unroll
            for (int kk = 0; kk < NKK; ++kk)
                kf[mf][kk] = *(const bf16x8*)&kt[((size_t)b * N_PIX + k0 + w * 32 + mf * 16 + l15) * QSTR + kk * 32 + quad * 8];

        #pragma unroll
        for (int nt = 0; nt < 8; ++nt) {
            f32x4 a[2] = {};
            #pragma unroll
            for (int kk = 0; kk < NKK; ++kk)
                #pragma unroll
                for (int mf = 0; mf < 2; ++mf)
                    a[mf] = __builtin_amdgcn_mfma_f32_16x16x32_bf16(kf[mf][kk], qf[nt][kk], a[mf], 0, 0, 0);
            #pragma unroll
            for (int mf = 0; mf < 2; ++mf) {
                unsigned p = pack4_fp8(exp2f(a[mf][0]), exp2f(a[mf][1]),
                                       exp2f(a[mf][2]), exp2f(a[mf][3]));
                *(unsigned*)&Ss[cur][(nt * 16 + l15) * 144 + w * 32 + mf * 16 + quad * 4] = p;
            }
        }
        __syncthreads();
        // coalesced fp8 write (64B per thread per row-half)
        int ql = t >> 1, kh = (t & 1) * 64;
        size_t row = ((size_t)b * N_PIX + q0 + ql) * (size_t)N_PIX + k0 + kh;
        #pragma unroll
        for (int j = 0; j < 4; ++j)
            *(uint4*)&S[row + j * 16] = *(const uint4*)&Ss[cur][ql * 144 + kh + j * 16];
    }
}

// ---------------------------------------------------------------------------
// Attention kernel 2/2: FP8 PV GEMM, QROWSxCCH tile, 1024 threads/16 waves.
// pv_gemm13 (round-8 proven): 2-phase A/B dbuf via __syncthreads, 128B-row
// LDS + XOR cg swizzle, softmax denominators via ones-MFMA.
// [Round-9 depth-3 counted-vmcnt REGRESSED twice (r3: occupancy cliff;
//  r9: even at zero occupancy cost, MfmaUtil 48->41).  The hand-scheduled
//  step defeats compiler scheduling (guide m141); pv stays 2-phase.]
// attn1 <2,128>: 128q x 128c; attn2 <4,256>: 256q x 128c.
// ---------------------------------------------------------------------------
typedef __attribute__((address_space(1))) const void* gas1_t;
typedef __attribute__((address_space(3))) void* las3_t;

template <int NT, int QROWS>
__global__ __launch_bounds__(1024)
void pv_gemm13(const uint8_t* __restrict__ E, const uint8_t* __restrict__ vg,
               const __bf16* __restrict__ xin2,
               const float* __restrict__ gamma, float* __restrict__ out, int C) {
    constexpr int NQS = QROWS / 32;
    constexpr int NCS = 16 / NQS;
    constexpr int CCH = NT * 16 * NCS;
    constexpr int NPAIR = (N_PIX / QROWS) * BATCH;
    __shared__ uint8_t PshA[QROWS * 128];
    __shared__ uint8_t PshB[QROWS * 128];
    __shared__ uint8_t VshA[CCH * 128];
    __shared__ uint8_t VshB[CCH * 128];
    int t = threadIdx.x;
    int lane = t & 63, w = t >> 6;
    int l15 = lane & 15, quad = lane >> 4;
    int qs = w % NQS, cs = w / NQS;
    int bid = blockIdx.x;
    int pair = bid % NPAIR, cblk = bid / NPAIR;
    int qi = pair >> 2, b = pair & 3;
    int q0 = qi * QROWS, c0 = cblk * CCH;
    const uint8_t* Pb = E + ((size_t)b * N_PIX + q0) * (size_t)N_PIX;
    const uint8_t* Vb = vg + ((size_t)b * C + c0) * (size_t)N_PIX;

    int r8 = lane >> 3;           // row within 8-row chunk
    int cgl = (lane & 7) ^ r8;    // swizzled 16B column group to load

    const long ONES = 0x3838383838383838L;  // 8x fp8-e4m3 1.0

    f32x4 acc[2][NT] = {};
    f32x4 acc_s[2] = {};          // row-sum accumulators (per-lane own rows)

    auto stage = [&](uint8_t* Ps, uint8_t* Vs, int k0) {
        #pragma unroll
        for (int ch = 0; ch < QROWS / 128; ++ch) {
            int row0 = w * (QROWS / 16) + ch * 8;
            const uint8_t* g = Pb + (size_t)(row0 + r8) * N_PIX + k0 + cgl * 16;
            __builtin_amdgcn_global_load_lds((gas1_t)g, (las3_t)&Ps[row0 * 128], 16, 0, 0);
        }
        static_assert(CCH / 8 == 16, "V staging assumes 16 chunks");
        {
            int row0 = w * 8;
            const uint8_t* g = Vb + (size_t)(row0 + r8) * N_PIX + k0 + cgl * 16;
            __builtin_amdgcn_global_load_lds((gas1_t)g, (las3_t)&Vs[row0 * 128], 16, 0, 0);
        }
    };

    // XOR cg swizzle, phase-minimal bank pattern
    auto compute = [&](const uint8_t* Ps, const uint8_t* Vs) {
        #pragma unroll
        for (int kk = 0; kk < 4; ++kk) {
            long pa[2];
            #pragma unroll
            for (int mf = 0; mf < 2; ++mf) {
                int row = qs * 32 + mf * 16 + l15;
                int cg = (2 * kk + (quad >> 1)) ^ (row & 7);
                pa[mf] = *(const long*)&Ps[row * 128 + cg * 16 + (quad & 1) * 8];
            }
            #pragma unroll
            for (int mf = 0; mf < 2; ++mf)
                acc_s[mf] = __builtin_amdgcn_mfma_f32_16x16x32_fp8_fp8(pa[mf], ONES, acc_s[mf], 0, 0, 0);
            #pragma unroll
            for (int nt = 0; nt < NT; ++nt) {
                int row = cs * (NT * 16) + nt * 16 + l15;
                int cg = (2 * kk + (quad >> 1)) ^ (row & 7);
                long vf = *(const long*)&Vs[row * 128 + cg * 16 + (quad & 1) * 8];
                #pragma unroll
                for (int mf = 0; mf < 2; ++mf)
                    acc[mf][nt] = __builtin_amdgcn_mfma_f32_16x16x32_fp8_fp8(pa[mf], vf, acc[mf][nt], 0, 0, 0);
            }
        }
    };

    stage(PshA, VshA, 0);
    __syncthreads();  // tile 0 staged

    for (int k0 = 0; k0 < N_PIX; k0 += 256) {
        stage(PshB, VshB, k0 + 128);   // prefetch next tile (always valid)
        compute(PshA, VshA);
        __syncthreads();               // vmcnt drain: B landed; all done with A
        if (k0 + 256 < N_PIX) stage(PshA, VshA, k0 + 256);
        compute(PshB, VshB);
        __syncthreads();               // A landed; all done with B
    }

    float g = gamma[0];
    #pragma unroll
    for (int mf = 0; mf < 2; ++mf)
        #pragma unroll
        for (int r = 0; r < 4; ++r) {
            int ql = qs * 32 + mf * 16 + quad * 4 + r;
            int q = q0 + ql;
            float gil = g / acc_s[mf][r];
            size_t xrb = ((size_t)b * N_PIX + q) * 2 * C;
            size_t orb = ((size_t)b * N_PIX + q) * C;
            #pragma unroll
            for (int nt = 0; nt < NT; ++nt) {
                int c = c0 + cs * (NT * 16) + nt * 16 + l15;
                float xr = (float)xin2[xrb + c] + (float)xin2[xrb + C + c];
                out[orb + c] = gil * acc[mf][nt][r] + xr;
            }
        }
}

// ---------------------------------------------------------------------------
// L5: out[b,n] = lrelu(iv * dot(W5, h[b,n,:]) + b5).  h: (B,N,512) fp32.
// ---------------------------------------------------------------------------
__global__ __launch_bounds__(256)
void l5_kernel(const float* __restrict__ h, const float* __restrict__ W5,
               const float* __restrict__ b5, const float* __restrict__ sig,
               float* __restrict__ out) {
    int t = threadIdx.x;
    int lane = t & 63, w = t >> 6;
    int p = blockIdx.x * 4 + w;
    const float* row = h + (size_t)p * 512;
    float4 a0 = *(const float4*)&row[lane * 8];
    float4 a1 = *(const float4*)&row[lane * 8 + 4];
    float4 w0 = *(const float4*)&W5[lane * 8];
    float4 w1 = *(const float4*)&W5[lane * 8 + 4];
    float s = a0.x * w0.x + a0.y * w0.y + a0.z * w0.z + a0.w * w0.w +
              a1.x * w1.x + a1.y * w1.y + a1.z * w1.z + a1.w * w1.w;
    #pragma unroll
    for (int off = 1; off < 64; off <<= 1) s += __shfl_xor(s, off);
    if (lane == 0) {
        float v = sig[0] * s + b5[0];
        out[p] = (v > 0.f) ? v : 0.1f * v;
    }
}

// ---------------------------------------------------------------------------
// Launcher
// ---------------------------------------------------------------------------
extern "C" void kernel_launch(void* const* d_in, const int* in_sizes, int n_in,
                              void* d_out, int out_size, void* d_ws, size_t ws_size,
                              hipStream_t stream) {
    const float* x   = (const float*)d_in[0];
    const float* W1  = (const float*)d_in[1];
    const float* b1  = (const float*)d_in[2];
    const float* u1  = (const float*)d_in[3];
    const float* W2  = (const float*)d_in[4];
    const float* b2  = (const float*)d_in[5];
    const float* u2  = (const float*)d_in[6];
    const float* W3  = (const float*)d_in[7];
    const float* b3  = (const float*)d_in[8];
    const float* u3  = (const float*)d_in[9];
    const float* W4  = (const float*)d_in[10];
    const float* b4  = (const float*)d_in[11];
    const float* u4  = (const float*)d_in[12];
    const float* W5  = (const float*)d_in[13];
    const float* b5  = (const float*)d_in[14];
    const float* u5  = (const float*)d_in[15];
    const float* a1_qW = (const float*)d_in[16];
    const float* a1_qb = (const float*)d_in[17];
    const float* a1_kW = (const float*)d_in[18];
    const float* a1_kb = (const float*)d_in[19];
    const float* a1_vW = (const float*)d_in[20];
    const float* a1_vb = (const float*)d_in[21];
    const float* a1_g  = (const float*)d_in[22];
    const float* a2_qW = (const float*)d_in[23];
    const float* a2_qb = (const float*)d_in[24];
    const float* a2_kW = (const float*)d_in[25];
    const float* a2_kb = (const float*)d_in[26];
    const float* a2_vW = (const float*)d_in[27];
    const float* a2_vb = (const float*)d_in[28];
    const float* a2_g  = (const float*)d_in[29];

    float* ws = (float*)d_ws;
    const size_t NF = (size_t)BATCH * N_PIX;  // 16384
    float* sig    = ws;                       // 16
    float* h1     = ws + 16;                  // NF*64 fl
    float* slabC  = h1 + NF * 64;             // NF*512 fl
    float* slabS1 = slabC + NF * 512;         // NF*256 fl
    float* slabS2 = slabS1 + NF * 256;        // NF*512 fl
    float* qtf    = slabS2 + NF * 512;        // NF*32 fl
    float* ktf    = qtf + NF * 32;            // NF*32 fl
    float* wspf   = ktf + NF * 32;            // ~0.58M fl weights
    float* bbf    = wspf + 592000;            // 192 fl bias concat
    float* ysig   = wspf + 592256;            // sigma scratch: y[5*512]+S1[5]+S2[5]
    float* Sf     = wspf + 600000;            // E: NF*4096 fp8 bytes

    __bf16* h1t = (__bf16*)slabS1;            // (B,N,128)
    __bf16* h2t = (__bf16*)slabS2;            // (B,N,256)
    __bf16* h3t = (__bf16*)slabS1;            // (B,N,512)
    __bf16* h5t = (__bf16*)slabS2;            // (B,N,1024)
    float*  h4t = slabC;                      // (B,N,256) fp32
    uint8_t* vb1 = (uint8_t*)(slabC + NF * 256);  // (B,256,N) fp8
    float*  h6t = slabC;                      // (B,N,512) fp32
    uint8_t* vb2 = (uint8_t*)slabS1;          // (B,512,N) fp8
    __bf16* qkt = (__bf16*)qtf;               // (B,N,2CQ) packed [q|k]
    __bf16* wsp = (__bf16*)wspf;
    uint8_t* Sbuf = (uint8_t*)Sf;             // (B,4096,4096) fp8

    float* ybuf = ysig;                       // 5*512
    float* S1v  = ysig + 2560;                // 5 (16-aligned pad below)
    float* S2v  = ysig + 2576;                // 5

    __bf16* wsL2  = wsp;            // 128*128
    __bf16* wsL3  = wsL2 + 16384;   // 256*256
    __bf16* wsL4  = wsL3 + 65536;   // 512*512
    __bf16* wsA1q = wsL4 + 262144;  // 32*512   [combined with wsA1k]
    __bf16* wsA1k = wsA1q + 16384;
    __bf16* wsA1v = wsA1k + 16384;  // 256*512
    __bf16* wsA2q = wsA1v + 131072; // 64*1024  [combined with wsA2k]
    __bf16* wsA2k = wsA2q + 65536;
    __bf16* wsA2v = wsA2k + 65536;  // 512*1024

    dim3 blk(256);

    SigP sp;
    sp.W[0] = W1; sp.u[0] = u1; sp.O[0] = 64;  sp.C[0] = 6;
    sp.W[1] = W2; sp.u[1] = u2; sp.O[1] = 128; sp.C[1] = 64;
    sp.W[2] = W3; sp.u[2] = u3; sp.O[2] = 256; sp.C[2] = 128;
    sp.W[3] = W4; sp.u[3] = u4; sp.O[3] = 512; sp.C[3] = 256;
    sp.W[4] = W5; sp.u[4] = u5; sp.O[4] = 1;   sp.C[4] = 512;

    hipMemsetAsync(ysig, 0, 2592 * sizeof(float), stream);
    sigma_p1<<<dim3(16), blk, 0, stream>>>(sp, ybuf);
    sigma_p2<<<dim3(16), blk, 0, stream>>>(sp, ybuf, S1v, S2v);
    concat_bias<<<1, blk, 0, stream>>>(a1_qb, a1_kb, a2_qb, a2_kb, bbf, S1v, S2v, sig);

    wsplit_kernel<<<128, blk, 0, stream>>>(W2, sig + 1, 1.f, 64, wsL2);
    wsplit_kernel<<<256, blk, 0, stream>>>(W3, sig + 2, 1.f, 128, wsL3);
    wsplit_kernel<<<512, blk, 0, stream>>>(W4, sig + 3, 1.f, 256, wsL4);
    wsplit_kernel<<<32,  blk, 0, stream>>>(a1_qW, nullptr, LOG2E, 256, wsA1q);
    wsplit_kernel<<<32,  blk, 0, stream>>>(a1_kW, nullptr, 1.f, 256, wsA1k);
    wsplit_kernel<<<256, blk, 0, stream>>>(a1_vW, nullptr, 1.f, 256, wsA1v);
    wsplit_kernel<<<64,  blk, 0, stream>>>(a2_qW, nullptr, LOG2E, 512, wsA2q);
    wsplit_kernel<<<64,  blk, 0, stream>>>(a2_kW, nullptr, 1.f, 512, wsA2k);
    wsplit_kernel<<<512, blk, 0, stream>>>(a2_vW, nullptr, 1.f, 512, wsA2v);

    // L1 (fp32) + transpose/split
    conv_f32_kernel<<<dim3(64, 1, 4), blk, 0, stream>>>(x, W1, b1, sig + 0, h1, 6, 64, 1);
    tsplit64_kernel<<<dim3(64, 4), blk, 0, stream>>>(h1, h1t);

    // L2, L3 (split-MFMA, MF=1)
    mfma_conv<4, 1, 1, 2, 0, 1><<<dim3(32, 2, 4), blk, 0, stream>>>(h1t, wsL2, b2, 1.f, h2t, 64, 128);
    mfma_conv<4, 1, 1, 2, 0, 1><<<dim3(32, 4, 4), blk, 0, stream>>>(h2t, wsL3, b3, 1.f, h3t, 128, 256);

    // attention 1 (C=256, Cq=32)
    mfma_conv<2, 2, 1, 4, 0, 0><<<dim3(16, 2, 4), blk, 0, stream>>>(h3t, wsA1q, bbf, 1.f, qkt, 256, 64);
    mfma_conv<4, 1, 1, 1, 0, 0><<<dim3(32, 4, 4), blk, 0, stream>>>(h3t, wsA1v, a1_vb, 1.f, vb1, 256, 256);
    s_gemm3<32, 8><<<dim3(4, 32, 4), blk, 0, stream>>>(qkt, qkt + 32, Sbuf, 64);
    pv_gemm13<2, 128><<<dim3(256), dim3(1024), 0, stream>>>(Sbuf, vb1, h3t, a1_g, h4t, 256);

    // L4 (fp32-transposed input)
    mfma_conv<4, 1, 1, 2, 1, 1><<<dim3(32, 8, 4), blk, 0, stream>>>(h4t, wsL4, b4, 1.f, h5t, 256, 512);

    // attention 2 (C=512, Cq=64)
    mfma_conv<2, 2, 1, 4, 0, 0><<<dim3(16, 4, 4), blk, 0, stream>>>(h5t, wsA2q, bbf + 64, 1.f, qkt, 512, 128);
    mfma_conv<4, 1, 1, 1, 0, 0><<<dim3(32, 8, 4), blk, 0, stream>>>(h5t, wsA2v, a2_vb, 1.f, vb2, 512, 512);
    s_gemm3<64, 8><<<dim3(4, 32, 4), blk, 0, stream>>>(qkt, qkt + 64, Sbuf, 128);
    pv_gemm13<4, 256><<<dim3(256), dim3(1024), 0, stream>>>(Sbuf, vb2, h5t, a2_g, h6t, 512);

    // L5
    l5_kernel<<<4096, blk, 0, stream>>>(h6t, W5, b5, sig + 4, (float*)d_out);
}

// Round 12
// 505.187 us; speedup vs baseline: 1.0682x; 1.0419x over previous
//
#include <hip/hip_runtime.h>
#include <math.h>

#define N_PIX 4096  // H*W = 64*64
#define BATCH 4
#define LOG2E 1.4426950408889634f

typedef __bf16 bf16x8 __attribute__((ext_vector_type(8)));
typedef __bf16 bf16x4v __attribute__((ext_vector_type(4)));
typedef float f32x4 __attribute__((ext_vector_type(4)));

// fp8 e4m3 (OCP on gfx950) pack/unpack via HW cvt builtins
__device__ __forceinline__ unsigned pack4_fp8(float a, float b, float c, float d) {
    unsigned p = __builtin_amdgcn_cvt_pk_fp8_f32(a, b, 0, false);
    p = __builtin_amdgcn_cvt_pk_fp8_f32(c, d, p, true);
    return p;
}
__device__ __forceinline__ uint8_t to_fp8(float v) {
    return (uint8_t)(__builtin_amdgcn_cvt_pk_fp8_f32(v, v, 0, false) & 0xff);
}

// ---------------------------------------------------------------------------
// Spectral norm, parallel, atomic-free.
// sigma = ||W (W^T u)|| / ||W^T u||  (intermediate normalization cancels).
// p1: each (L,chunk) block writes its W^T u partial to ybuf[bid][512].
// p2: sums its layer's chunk partials (ysh), computes S1[L] (chunk-0 block,
//     direct write) and per-block ||W y||^2 partial S2p[bid].
// concat_bias: folds S2p chunks -> sig[L].  No atomics, no memset.
// ---------------------------------------------------------------------------
struct SigP {
    const float* W[5];
    const float* u[5];
    int O[5];
    int C[5];
};

// block -> (layer, 64-row chunk): counts {1,2,4,8,1}, bases {0,1,3,7,15}
__device__ __forceinline__ void sig_map(int bid, int& L, int& ch) {
    if (bid == 0)      { L = 0; ch = 0; }
    else if (bid < 3)  { L = 1; ch = bid - 1; }
    else if (bid < 7)  { L = 2; ch = bid - 3; }
    else if (bid < 15) { L = 3; ch = bid - 7; }
    else               { L = 4; ch = 0; }
}

__global__ __launch_bounds__(256)
void sigma_p1(SigP p, float* __restrict__ ybuf) {
    __shared__ float ush[64];
    int L, ch;
    sig_map(blockIdx.x, L, ch);
    const float* W = p.W[L];
    const float* u = p.u[L];
    int O = p.O[L], C = p.C[L];
    int o0 = ch * 64;
    int no = O - o0; if (no > 64) no = 64;
    int t = threadIdx.x;
    if (t < 64) ush[t] = (t < no) ? u[o0 + t] : 0.f;
    __syncthreads();
    for (int c = t; c < C; c += 256) {
        float a = 0.f;
        for (int o = 0; o < no; ++o) a += W[(size_t)(o0 + o) * C + c] * ush[o];
        ybuf[(size_t)blockIdx.x * 512 + c] = a;
    }
}

__global__ __launch_bounds__(256)
void sigma_p2(SigP p, const float* __restrict__ ybuf,
              float* __restrict__ S1, float* __restrict__ S2p) {
    __shared__ float ysh[512];
    __shared__ float red[8];
    int L, ch;
    sig_map(blockIdx.x, L, ch);
    const int baseT[5] = {0, 1, 3, 7, 15};
    const int cntT[5]  = {1, 2, 4, 8, 1};
    int base = baseT[L], cnt = cntT[L];
    const float* W = p.W[L];
    int O = p.O[L], C = p.C[L];
    int o0 = ch * 64;
    int o_hi = o0 + 64; if (o_hi > O) o_hi = O;
    int t = threadIdx.x;
    int lane = t & 63, w = t >> 6;
    for (int c = t; c < C; c += 256) {
        float s = 0.f;
        for (int i = 0; i < cnt; ++i) s += ybuf[(size_t)(base + i) * 512 + c];
        ysh[c] = s;
    }
    __syncthreads();

    if (ch == 0) {
        float s = 0.f;
        for (int c = t; c < C; c += 256) s += ysh[c] * ysh[c];
        #pragma unroll
        for (int off = 1; off < 64; off <<= 1) s += __shfl_xor(s, off);
        if (lane == 0) red[w] = s;
    }

    float sq = 0.f;
    for (int i = 0; i < 16; ++i) {
        int o = o0 + w * 16 + i;
        if (o >= o_hi) break;
        float a = 0.f;
        for (int c = lane; c < C; c += 64) a += W[(size_t)o * C + c] * ysh[c];
        #pragma unroll
        for (int off = 1; off < 64; off <<= 1) a += __shfl_xor(a, off);
        if (lane == 0) sq += a * a;
    }
    if (lane == 0) red[4 + w] = sq;
    __syncthreads();
    if (t == 0) {
        if (ch == 0) S1[L] = red[0] + red[1] + red[2] + red[3];
        S2p[blockIdx.x] = red[4] + red[5] + red[6] + red[7];
    }
}

// ---------------------------------------------------------------------------
// All 9 weight splits in ONE launch.  block -> (segment, row).
// (O,C) fp32 * sig[idx] * scale -> (O, 2C) bf16 [hi | lo].
// ---------------------------------------------------------------------------
struct WsAll {
    const float* W[9];
    __bf16* out[9];
    int C[9];
    int sigidx[9];
    float scale[9];
    int end[9];   // cumulative row counts
};

__global__ __launch_bounds__(256)
void wsplit_all(WsAll p, const float* __restrict__ sig) {
    int bid = blockIdx.x;
    int s = 0;
    #pragma unroll
    for (int i = 0; i < 9; ++i)
        if (bid >= p.end[i]) s = i + 1;
    int o = bid - (s ? p.end[s - 1] : 0);
    const float* W = p.W[s];
    __bf16* out = p.out[s];
    int C = p.C[s];
    float sc = (p.sigidx[s] >= 0 ? sig[p.sigidx[s]] : 1.f) * p.scale[s];
    for (int c = threadIdx.x; c < C; c += 256) {
        float wv = W[(size_t)o * C + c] * sc;
        __bf16 hi = (__bf16)wv;
        out[(size_t)o * 2 * C + c] = hi;
        out[(size_t)o * 2 * C + C + c] = (__bf16)(wv - (float)hi);
    }
}

// ---------------------------------------------------------------------------
// Concat + prescale attention biases; ALSO finishes sigma (phase 3).
// ---------------------------------------------------------------------------
__global__ __launch_bounds__(256)
void concat_bias(const float* __restrict__ qb1, const float* __restrict__ kb1,
                 const float* __restrict__ qb2, const float* __restrict__ kb2,
                 float* __restrict__ bb,
                 const float* __restrict__ S1, const float* __restrict__ S2p,
                 float* __restrict__ sig) {
    int t = threadIdx.x;
    if (t < 32) bb[t] = qb1[t] * LOG2E;
    else if (t < 64) bb[t] = kb1[t - 32];
    else if (t < 128) bb[t] = qb2[t - 64] * LOG2E;
    else if (t < 192) bb[t] = kb2[t - 128];
    else if (t >= 224 && t < 229) {
        int L = t - 224;
        const int baseT[5] = {0, 1, 3, 7, 15};
        const int cntT[5]  = {1, 2, 4, 8, 1};
        float s2 = 0.f;
        for (int i = 0; i < cntT[L]; ++i) s2 += S2p[baseT[L] + i];
        float rinv = 1.f / (sqrtf(S1[L]) + 1e-12f);
        float ns2 = rinv * rinv * s2;
        float sg = ns2 / (sqrtf(ns2) + 1e-12f);
        sig[L] = 1.f / sg;
    }
}

// ---------------------------------------------------------------------------
// L1 fused: fp32 VALU conv (C=6, O=64) + in-LDS transpose/split directly to
// (B,N,128) bf16 [hi(64)|lo(64)].  Replaces conv_f32 + tsplit64 and the 8MB
// h1 round-trip.  Block = 64n x all 64 o.
// ---------------------------------------------------------------------------
__global__ __launch_bounds__(256)
void conv1_kernel(const float* __restrict__ x, const float* __restrict__ W,
                  const float* __restrict__ bias, const float* __restrict__ sig,
                  __bf16* __restrict__ out) {
    constexpr int C = 6;
    __shared__ float Ws[16][68];
    __shared__ float Xs[16][68];
    __shared__ float tile[64 * 65];
    int t = threadIdx.x;
    int tx = t & 15, ty = t >> 4;
    int b = blockIdx.z;
    int n0 = blockIdx.x * 64;
    float acc[4][4] = {};
    const float* xb = x + (size_t)b * C * N_PIX;

    #pragma unroll
    for (int i = 0; i < 4; ++i) {
        int e = t + i * 256;
        int o = e >> 4, c = e & 15;
        Ws[c][o] = (c < C) ? W[(size_t)o * C + c] : 0.f;
    }
    #pragma unroll
    for (int i = 0; i < 4; ++i) {
        int e = t + i * 256;
        int c = e >> 6, n = e & 63;
        Xs[c][n] = (c < C) ? xb[(size_t)c * N_PIX + n0 + n] : 0.f;
    }
    __syncthreads();
    #pragma unroll
    for (int cc = 0; cc < 16; ++cc) {
        float4 wv = *(const float4*)&Ws[cc][ty * 4];
        float4 xv = *(const float4*)&Xs[cc][tx * 4];
        float wa[4] = {wv.x, wv.y, wv.z, wv.w};
        float xa[4] = {xv.x, xv.y, xv.z, xv.w};
        #pragma unroll
        for (int i = 0; i < 4; ++i)
            #pragma unroll
            for (int j = 0; j < 4; ++j)
                acc[i][j] += wa[i] * xa[j];
    }

    float ivv = sig[0];
    #pragma unroll
    for (int i = 0; i < 4; ++i) {
        int o = ty * 4 + i;
        float bv = bias[o];
        #pragma unroll
        for (int j = 0; j < 4; ++j) {
            float v = acc[i][j] * ivv + bv;
            v = (v > 0.f) ? v : 0.1f * v;
            tile[(tx * 4 + j) * 65 + o] = v;
        }
    }
    __syncthreads();
    for (int e = t; e < 64 * 64; e += 256) {
        int n = e >> 6, c = e & 63;
        float v = tile[n * 65 + c];
        __bf16 hi = (__bf16)v;
        size_t base = ((size_t)b * N_PIX + n0 + n) * 128;
        out[base + c] = hi;
        out[base + 64 + c] = (__bf16)(v - (float)hi);
    }
}

// ---------------------------------------------------------------------------
// Split-bf16 MFMA 1x1 conv. MF = m-frags per wave (1 or 2).
// MODE 1 emits fp8-e4m3 (B,O,N) for the attention V buffers.
// ---------------------------------------------------------------------------
template <int WO, int WN, int MF, int MODE, int IN_F32, int LRELU>
__global__ __launch_bounds__(256)
void mfma_conv(const void* __restrict__ xt, const __bf16* __restrict__ wsp,
               const float* __restrict__ bias, float bscale,
               void* __restrict__ outp, int C, int O) {
    constexpr int NT_BLK = WN * 128;
    constexpr int OT_BLK = WO * 16 * MF;
    __shared__ __bf16 Ws[OT_BLK * 72];
    __shared__ __bf16 Xs[NT_BLK * 72];
    int t = threadIdx.x;
    int lane = t & 63, w = t >> 6;
    int l15 = lane & 15, quad = lane >> 4;
    int wo = w / WN, wn = w % WN;
    int b = blockIdx.z;
    int n0b = blockIdx.x * NT_BLK, o0b = blockIdx.y * OT_BLK;

    f32x4 acc[MF][8] = {};

    for (int c0 = 0; c0 < C; c0 += 32) {
        __syncthreads();
        for (int e = t; e < OT_BLK * 8; e += 256) {
            int row = e >> 3, part = e & 7;
            size_t src = (size_t)(o0b + row) * 2 * C +
                         (part < 4 ? c0 + part * 8 : C + c0 + (part - 4) * 8);
            int dst = row * 72 + (part < 4 ? part * 8 : 32 + (part - 4) * 8);
            *(uint4*)&Ws[dst] = *(const uint4*)&wsp[src];
        }
        if (IN_F32) {
            const float* xf = (const float*)xt;
            for (int e = t; e < NT_BLK * 8; e += 256) {
                int row = e >> 3, part = e & 7;
                float4 v = *(const float4*)&xf[((size_t)b * N_PIX + n0b + row) * C + c0 + part * 4];
                bf16x4v hi, lo;
                float va[4] = {v.x, v.y, v.z, v.w};
                #pragma unroll
                for (int j = 0; j < 4; ++j) {
                    hi[j] = (__bf16)va[j];
                    lo[j] = (__bf16)(va[j] - (float)hi[j]);
                }
                *(bf16x4v*)&Xs[row * 72 + part * 4] = hi;
                *(bf16x4v*)&Xs[row * 72 + 32 + part * 4] = lo;
            }
        } else {
            const __bf16* xb = (const __bf16*)xt;
            for (int e = t; e < NT_BLK * 8; e += 256) {
                int row = e >> 3, part = e & 7;
                size_t src = ((size_t)b * N_PIX + n0b + row) * 2 * C +
                             (part < 4 ? c0 + part * 8 : C + c0 + (part - 4) * 8);
                int dst = row * 72 + (part < 4 ? part * 8 : 32 + (part - 4) * 8);
                *(uint4*)&Xs[dst] = *(const uint4*)&xb[src];
            }
        }
        __syncthreads();

        bf16x8 ah[MF], al[MF];
        #pragma unroll
        for (int mf = 0; mf < MF; ++mf) {
            int base = (wo * 16 * MF + mf * 16 + l15) * 72 + quad * 8;
            ah[mf] = *(const bf16x8*)&Ws[base];
            al[mf] = *(const bf16x8*)&Ws[base + 32];
        }
        #pragma unroll
        for (int nt = 0; nt < 8; ++nt) {
            int bbase = (wn * 128 + nt * 16 + l15) * 72 + quad * 8;
            bf16x8 bh = *(const bf16x8*)&Xs[bbase];
            bf16x8 bl = *(const bf16x8*)&Xs[bbase + 32];
            #pragma unroll
            for (int mf = 0; mf < MF; ++mf) {
                acc[mf][nt] = __builtin_amdgcn_mfma_f32_16x16x32_bf16(ah[mf], bh, acc[mf][nt], 0, 0, 0);
                acc[mf][nt] = __builtin_amdgcn_mfma_f32_16x16x32_bf16(ah[mf], bl, acc[mf][nt], 0, 0, 0);
                acc[mf][nt] = __builtin_amdgcn_mfma_f32_16x16x32_bf16(al[mf], bh, acc[mf][nt], 0, 0, 0);
            }
        }
    }

    float bv[MF][4];
    #pragma unroll
    for (int mf = 0; mf < MF; ++mf)
        #pragma unroll
        for (int r = 0; r < 4; ++r)
            bv[mf][r] = bias[o0b + wo * 16 * MF + mf * 16 + quad * 4 + r] * bscale;

    #pragma unroll
    for (int mf = 0; mf < MF; ++mf)
        #pragma unroll
        for (int nt = 0; nt < 8; ++nt) {
            int n = n0b + wn * 128 + nt * 16 + l15;
            float val[4];
            #pragma unroll
            for (int r = 0; r < 4; ++r) {
                float v = acc[mf][nt][r] + bv[mf][r];
                if (LRELU) v = (v > 0.f) ? v : 0.1f * v;
                val[r] = v;
            }
            int obase = o0b + wo * 16 * MF + mf * 16 + quad * 4;
            if (MODE == 1) {  // fp8 (B,O,N) for attention V
                uint8_t* ob = (uint8_t*)outp;
                #pragma unroll
                for (int r = 0; r < 4; ++r)
                    ob[((size_t)b * O + obase + r) * N_PIX + n] = to_fp8(val[r]);
            } else if (MODE == 2) {
                __bf16* ob = (__bf16*)outp;
                bf16x4v hv, lv;
                #pragma unroll
                for (int r = 0; r < 4; ++r) {
                    hv[r] = (__bf16)val[r];
                    lv[r] = (__bf16)(val[r] - (float)hv[r]);
                }
                size_t rb = ((size_t)b * N_PIX + n) * 2 * O + obase;
                *(bf16x4v*)&ob[rb] = hv;
                *(bf16x4v*)&ob[rb + O] = lv;
            } else {  // MODE 4
                __bf16* ob = (__bf16*)outp;
                bf16x4v hv;
                #pragma unroll
                for (int r = 0; r < 4; ++r) hv[r] = (__bf16)val[r];
                *(bf16x4v*)&ob[((size_t)b * N_PIX + n) * O + obase] = hv;
            }
        }
}

// ---------------------------------------------------------------------------
// Attention kernel 1/2: E = exp2(qk-dot) -> FP8-e4m3.
// KITER k-tiles per block, q fragments loaded once; double-buffered Ss
// (one __syncthreads per k-tile).
// ---------------------------------------------------------------------------
template <int CQ, int KITER>
__global__ __launch_bounds__(256)
void s_gemm3(const __bf16* __restrict__ qt, const __bf16* __restrict__ kt,
             uint8_t* __restrict__ S, int QSTR) {
    constexpr int NKK = CQ / 32;
    __shared__ uint8_t Ss[2][128 * 144];
    int t = threadIdx.x;
    int lane = t & 63, w = t >> 6;
    int l15 = lane & 15, quad = lane >> 4;
    int kbase = blockIdx.x * KITER * 128, q0 = blockIdx.y * 128, b = blockIdx.z;

    bf16x8 qf[8][NKK];
    #pragma unroll
    for (int nt = 0; nt < 8; ++nt)
        #pragma unroll
        for (int kk = 0; kk < NKK; ++kk)
            qf[nt][kk] = *(const bf16x8*)&qt[((size_t)b * N_PIX + q0 + nt * 16 + l15) * QSTR + kk * 32 + quad * 8];

    for (int ki = 0; ki < KITER; ++ki) {
        int k0 = kbase + ki * 128;
        int cur = ki & 1;
        bf16x8 kf[2][NKK];
        #pragma unroll
        for (int mf = 0; mf < 2; ++mf)
            #pragma unroll
            for (int kk = 0; kk < NKK; ++kk)
                kf[mf][kk] = *(const bf16x8*)&kt[((size_t)b * N_PIX + k0 + w * 32 + mf * 16 + l15) * QSTR + kk * 32 + quad * 8];

        #pragma unroll
        for (int nt = 0; nt < 8; ++nt) {
            f32x4 a[2] = {};
            #pragma unroll
            for (int kk = 0; kk < NKK; ++kk)
                #pragma unroll
                for (int mf = 0; mf < 2; ++mf)
                    a[mf] = __builtin_amdgcn_mfma_f32_16x16x32_bf16(kf[mf][kk], qf[nt][kk], a[mf], 0, 0, 0);
            #pragma unroll
            for (int mf = 0; mf < 2; ++mf) {
                unsigned p = pack4_fp8(exp2f(a[mf][0]), exp2f(a[mf][1]),
                                       exp2f(a[mf][2]), exp2f(a[mf][3]));
                *(unsigned*)&Ss[cur][(nt * 16 + l15) * 144 + w * 32 + mf * 16 + quad * 4] = p;
            }
        }
        __syncthreads();
        // coalesced fp8 write (64B per thread per row-half)
        int ql = t >> 1, kh = (t & 1) * 64;
        size_t row = ((size_t)b * N_PIX + q0 + ql) * (size_t)N_PIX + k0 + kh;
        #pragma unroll
        for (int j = 0; j < 4; ++j)
            *(uint4*)&S[row + j * 16] = *(const uint4*)&Ss[cur][ql * 144 + kh + j * 16];
    }
}

// ---------------------------------------------------------------------------
// Attention kernel 2/2: FP8 PV GEMM, QROWSxCCH tile, 1024 threads/16 waves.
// pv_gemm13 (round-8 proven): 2-phase A/B dbuf via __syncthreads, 128B-row
// LDS + XOR cg swizzle, softmax denominators via ones-MFMA.
// [Depth-3 counted-vmcnt regressed twice (r3, r9) -- pv stays 2-phase.]
// attn1 <2,128>: 128q x 128c; attn2 <4,256>: 256q x 128c.
// ---------------------------------------------------------------------------
typedef __attribute__((address_space(1))) const void* gas1_t;
typedef __attribute__((address_space(3))) void* las3_t;

template <int NT, int QROWS>
__global__ __launch_bounds__(1024)
void pv_gemm13(const uint8_t* __restrict__ E, const uint8_t* __restrict__ vg,
               const __bf16* __restrict__ xin2,
               const float* __restrict__ gamma, float* __restrict__ out, int C) {
    constexpr int NQS = QROWS / 32;
    constexpr int NCS = 16 / NQS;
    constexpr int CCH = NT * 16 * NCS;
    constexpr int NPAIR = (N_PIX / QROWS) * BATCH;
    __shared__ uint8_t PshA[QROWS * 128];
    __shared__ uint8_t PshB[QROWS * 128];
    __shared__ uint8_t VshA[CCH * 128];
    __shared__ uint8_t VshB[CCH * 128];
    int t = threadIdx.x;
    int lane = t & 63, w = t >> 6;
    int l15 = lane & 15, quad = lane >> 4;
    int qs = w % NQS, cs = w / NQS;
    int bid = blockIdx.x;
    int pair = bid % NPAIR, cblk = bid / NPAIR;
    int qi = pair >> 2, b = pair & 3;
    int q0 = qi * QROWS, c0 = cblk * CCH;
    const uint8_t* Pb = E + ((size_t)b * N_PIX + q0) * (size_t)N_PIX;
    const uint8_t* Vb = vg + ((size_t)b * C + c0) * (size_t)N_PIX;

    int r8 = lane >> 3;           // row within 8-row chunk
    int cgl = (lane & 7) ^ r8;    // swizzled 16B column group to load

    const long ONES = 0x3838383838383838L;  // 8x fp8-e4m3 1.0

    f32x4 acc[2][NT] = {};
    f32x4 acc_s[2] = {};          // row-sum accumulators (per-lane own rows)

    auto stage = [&](uint8_t* Ps, uint8_t* Vs, int k0) {
        #pragma unroll
        for (int ch = 0; ch < QROWS / 128; ++ch) {
            int row0 = w * (QROWS / 16) + ch * 8;
            const uint8_t* g = Pb + (size_t)(row0 + r8) * N_PIX + k0 + cgl * 16;
            __builtin_amdgcn_global_load_lds((gas1_t)g, (las3_t)&Ps[row0 * 128], 16, 0, 0);
        }
        static_assert(CCH / 8 == 16, "V staging assumes 16 chunks");
        {
            int row0 = w * 8;
            const uint8_t* g = Vb + (size_t)(row0 + r8) * N_PIX + k0 + cgl * 16;
            __builtin_amdgcn_global_load_lds((gas1_t)g, (las3_t)&Vs[row0 * 128], 16, 0, 0);
        }
    };

    // XOR cg swizzle, phase-minimal bank pattern
    auto compute = [&](const uint8_t* Ps, const uint8_t* Vs) {
        #pragma unroll
        for (int kk = 0; kk < 4; ++kk) {
            long pa[2];
            #pragma unroll
            for (int mf = 0; mf < 2; ++mf) {
                int row = qs * 32 + mf * 16 + l15;
                int cg = (2 * kk + (quad >> 1)) ^ (row & 7);
                pa[mf] = *(const long*)&Ps[row * 128 + cg * 16 + (quad & 1) * 8];
            }
            #pragma unroll
            for (int mf = 0; mf < 2; ++mf)
                acc_s[mf] = __builtin_amdgcn_mfma_f32_16x16x32_fp8_fp8(pa[mf], ONES, acc_s[mf], 0, 0, 0);
            #pragma unroll
            for (int nt = 0; nt < NT; ++nt) {
                int row = cs * (NT * 16) + nt * 16 + l15;
                int cg = (2 * kk + (quad >> 1)) ^ (row & 7);
                long vf = *(const long*)&Vs[row * 128 + cg * 16 + (quad & 1) * 8];
                #pragma unroll
                for (int mf = 0; mf < 2; ++mf)
                    acc[mf][nt] = __builtin_amdgcn_mfma_f32_16x16x32_fp8_fp8(pa[mf], vf, acc[mf][nt], 0, 0, 0);
            }
        }
    };

    stage(PshA, VshA, 0);
    __syncthreads();  // tile 0 staged

    for (int k0 = 0; k0 < N_PIX; k0 += 256) {
        stage(PshB, VshB, k0 + 128);   // prefetch next tile (always valid)
        compute(PshA, VshA);
        __syncthreads();               // vmcnt drain: B landed; all done with A
        if (k0 + 256 < N_PIX) stage(PshA, VshA, k0 + 256);
        compute(PshB, VshB);
        __syncthreads();               // A landed; all done with B
    }

    float g = gamma[0];
    #pragma unroll
    for (int mf = 0; mf < 2; ++mf)
        #pragma unroll
        for (int r = 0; r < 4; ++r) {
            int ql = qs * 32 + mf * 16 + quad * 4 + r;
            int q = q0 + ql;
            float gil = g / acc_s[mf][r];
            size_t xrb = ((size_t)b * N_PIX + q) * 2 * C;
            size_t orb = ((size_t)b * N_PIX + q) * C;
            #pragma unroll
            for (int nt = 0; nt < NT; ++nt) {
                int c = c0 + cs * (NT * 16) + nt * 16 + l15;
                float xr = (float)xin2[xrb + c] + (float)xin2[xrb + C + c];
                out[orb + c] = gil * acc[mf][nt][r] + xr;
            }
        }
}

// ---------------------------------------------------------------------------
// L5: out[b,n] = lrelu(iv * dot(W5, h[b,n,:]) + b5).  h: (B,N,512) fp32.
// ---------------------------------------------------------------------------
__global__ __launch_bounds__(256)
void l5_kernel(const float* __restrict__ h, const float* __restrict__ W5,
               const float* __restrict__ b5, const float* __restrict__ sig,
               float* __restrict__ out) {
    int t = threadIdx.x;
    int lane = t & 63, w = t >> 6;
    int p = blockIdx.x * 4 + w;
    const float* row = h + (size_t)p * 512;
    float4 a0 = *(const float4*)&row[lane * 8];
    float4 a1 = *(const float4*)&row[lane * 8 + 4];
    float4 w0 = *(const float4*)&W5[lane * 8];
    float4 w1 = *(const float4*)&W5[lane * 8 + 4];
    float s = a0.x * w0.x + a0.y * w0.y + a0.z * w0.z + a0.w * w0.w +
              a1.x * w1.x + a1.y * w1.y + a1.z * w1.z + a1.w * w1.w;
    #pragma unroll
    for (int off = 1; off < 64; off <<= 1) s += __shfl_xor(s, off);
    if (lane == 0) {
        float v = sig[0] * s + b5[0];
        out[p] = (v > 0.f) ? v : 0.1f * v;
    }
}

// ---------------------------------------------------------------------------
// Launcher
// ---------------------------------------------------------------------------
extern "C" void kernel_launch(void* const* d_in, const int* in_sizes, int n_in,
                              void* d_out, int out_size, void* d_ws, size_t ws_size,
                              hipStream_t stream) {
    const float* x   = (const float*)d_in[0];
    const float* W1  = (const float*)d_in[1];
    const float* b1  = (const float*)d_in[2];
    const float* u1  = (const float*)d_in[3];
    const float* W2  = (const float*)d_in[4];
    const float* b2  = (const float*)d_in[5];
    const float* u2  = (const float*)d_in[6];
    const float* W3  = (const float*)d_in[7];
    const float* b3  = (const float*)d_in[8];
    const float* u3  = (const float*)d_in[9];
    const float* W4  = (const float*)d_in[10];
    const float* b4  = (const float*)d_in[11];
    const float* u4  = (const float*)d_in[12];
    const float* W5  = (const float*)d_in[13];
    const float* b5  = (const float*)d_in[14];
    const float* u5  = (const float*)d_in[15];
    const float* a1_qW = (const float*)d_in[16];
    const float* a1_qb = (const float*)d_in[17];
    const float* a1_kW = (const float*)d_in[18];
    const float* a1_kb = (const float*)d_in[19];
    const float* a1_vW = (const float*)d_in[20];
    const float* a1_vb = (const float*)d_in[21];
    const float* a1_g  = (const float*)d_in[22];
    const float* a2_qW = (const float*)d_in[23];
    const float* a2_qb = (const float*)d_in[24];
    const float* a2_kW = (const float*)d_in[25];
    const float* a2_kb = (const float*)d_in[26];
    const float* a2_vW = (const float*)d_in[27];
    const float* a2_vb = (const float*)d_in[28];
    const float* a2_g  = (const float*)d_in[29];

    float* ws = (float*)d_ws;
    const size_t NF = (size_t)BATCH * N_PIX;  // 16384
    float* sig    = ws;                       // 16
    float* h1     = ws + 16;                  // NF*64 fl (unused scratch)
    float* slabC  = h1 + NF * 64;             // NF*512 fl
    float* slabS1 = slabC + NF * 512;         // NF*256 fl
    float* slabS2 = slabS1 + NF * 256;        // NF*512 fl
    float* qtf    = slabS2 + NF * 512;        // NF*32 fl
    float* ktf    = qtf + NF * 32;            // NF*32 fl
    float* wspf   = ktf + NF * 32;            // ~0.58M fl weights (ends 581632)
    float* bbf    = wspf + 592000;            // 192 fl bias concat
    float* Sf     = wspf + 600000;            // E: NF*4096 fp8 bytes

    __bf16* h1t = (__bf16*)slabS1;            // (B,N,128)
    __bf16* h2t = (__bf16*)slabS2;            // (B,N,256)
    __bf16* h3t = (__bf16*)slabS1;            // (B,N,512)
    __bf16* h5t = (__bf16*)slabS2;            // (B,N,1024)
    float*  h4t = slabC;                      // (B,N,256) fp32
    uint8_t* vb1 = (uint8_t*)(slabC + NF * 256);  // (B,256,N) fp8
    float*  h6t = slabC;                      // (B,N,512) fp32
    uint8_t* vb2 = (uint8_t*)slabS1;          // (B,512,N) fp8
    __bf16* qkt = (__bf16*)qtf;               // (B,N,2CQ) packed [q|k]
    __bf16* wsp = (__bf16*)wspf;
    uint8_t* Sbuf = (uint8_t*)Sf;             // (B,4096,4096) fp8

    // sigma scratch (after weights end at wspf+581632, before bbf)
    float* ybuf = wspf + 582000;              // 16*512 partials
    float* S1v  = wspf + 590200;              // 5
    float* S2p  = wspf + 590208;              // 16

    __bf16* wsL2  = wsp;            // 128*128
    __bf16* wsL3  = wsL2 + 16384;   // 256*256
    __bf16* wsL4  = wsL3 + 65536;   // 512*512
    __bf16* wsA1q = wsL4 + 262144;  // 32*512   [combined with wsA1k]
    __bf16* wsA1k = wsA1q + 16384;
    __bf16* wsA1v = wsA1k + 16384;  // 256*512
    __bf16* wsA2q = wsA1v + 131072; // 64*1024  [combined with wsA2k]
    __bf16* wsA2k = wsA2q + 65536;
    __bf16* wsA2v = wsA2k + 65536;  // 512*1024

    dim3 blk(256);

    SigP sp;
    sp.W[0] = W1; sp.u[0] = u1; sp.O[0] = 64;  sp.C[0] = 6;
    sp.W[1] = W2; sp.u[1] = u2; sp.O[1] = 128; sp.C[1] = 64;
    sp.W[2] = W3; sp.u[2] = u3; sp.O[2] = 256; sp.C[2] = 128;
    sp.W[3] = W4; sp.u[3] = u4; sp.O[3] = 512; sp.C[3] = 256;
    sp.W[4] = W5; sp.u[4] = u5; sp.O[4] = 1;   sp.C[4] = 512;

    sigma_p1<<<dim3(16), blk, 0, stream>>>(sp, ybuf);
    sigma_p2<<<dim3(16), blk, 0, stream>>>(sp, ybuf, S1v, S2p);
    concat_bias<<<1, blk, 0, stream>>>(a1_qb, a1_kb, a2_qb, a2_kb, bbf, S1v, S2p, sig);

    // all 9 weight splits in one launch
    WsAll wa;
    const float* wW[9]   = {W2, W3, W4, a1_qW, a1_kW, a1_vW, a2_qW, a2_kW, a2_vW};
    __bf16* wO[9]        = {wsL2, wsL3, wsL4, wsA1q, wsA1k, wsA1v, wsA2q, wsA2k, wsA2v};
    const int wC[9]      = {64, 128, 256, 256, 256, 256, 512, 512, 512};
    const int wSig[9]    = {1, 2, 3, -1, -1, -1, -1, -1, -1};
    const float wScl[9]  = {1.f, 1.f, 1.f, LOG2E, 1.f, 1.f, LOG2E, 1.f, 1.f};
    const int wRows[9]   = {128, 256, 512, 32, 32, 256, 64, 64, 512};
    int cum = 0;
    for (int i = 0; i < 9; ++i) {
        wa.W[i] = wW[i]; wa.out[i] = wO[i]; wa.C[i] = wC[i];
        wa.sigidx[i] = wSig[i]; wa.scale[i] = wScl[i];
        cum += wRows[i]; wa.end[i] = cum;
    }
    wsplit_all<<<dim3(cum), blk, 0, stream>>>(wa, sig);

    // L1 fused conv + transpose/split
    conv1_kernel<<<dim3(64, 1, 4), blk, 0, stream>>>(x, W1, b1, sig, h1t);

    // L2, L3 (split-MFMA, MF=1)
    mfma_conv<4, 1, 1, 2, 0, 1><<<dim3(32, 2, 4), blk, 0, stream>>>(h1t, wsL2, b2, 1.f, h2t, 64, 128);
    mfma_conv<4, 1, 1, 2, 0, 1><<<dim3(32, 4, 4), blk, 0, stream>>>(h2t, wsL3, b3, 1.f, h3t, 128, 256);

    // attention 1 (C=256, Cq=32)
    mfma_conv<2, 2, 1, 4, 0, 0><<<dim3(16, 2, 4), blk, 0, stream>>>(h3t, wsA1q, bbf, 1.f, qkt, 256, 64);
    mfma_conv<4, 1, 1, 1, 0, 0><<<dim3(32, 4, 4), blk, 0, stream>>>(h3t, wsA1v, a1_vb, 1.f, vb1, 256, 256);
    s_gemm3<32, 8><<<dim3(4, 32, 4), blk, 0, stream>>>(qkt, qkt + 32, Sbuf, 64);
    pv_gemm13<2, 128><<<dim3(256), dim3(1024), 0, stream>>>(Sbuf, vb1, h3t, a1_g, h4t, 256);

    // L4 (fp32-transposed input)
    mfma_conv<4, 1, 1, 2, 1, 1><<<dim3(32, 8, 4), blk, 0, stream>>>(h4t, wsL4, b4, 1.f, h5t, 256, 512);

    // attention 2 (C=512, Cq=64)
    mfma_conv<2, 2, 1, 4, 0, 0><<<dim3(16, 4, 4), blk, 0, stream>>>(h5t, wsA2q, bbf + 64, 1.f, qkt, 512, 128);
    mfma_conv<4, 1, 1, 1, 0, 0><<<dim3(32, 8, 4), blk, 0, stream>>>(h5t, wsA2v, a2_vb, 1.f, vb2, 512, 512);
    s_gemm3<64, 8><<<dim3(4, 32, 4), blk, 0, stream>>>(qkt, qkt + 64, Sbuf, 128);
    pv_gemm13<4, 256><<<dim3(256), dim3(1024), 0, stream>>>(Sbuf, vb2, h5t, a2_g, h6t, 512);

    // L5
    l5_kernel<<<4096, blk, 0, stream>>>(h6t, W5, b5, sig + 4, (float*)d_out);
}